// Round 17
// baseline (634.277 us; speedup 1.0000x reference)
//
#include <hip/hip_runtime.h>
#include <hip/hip_bf16.h>

typedef __hip_bfloat16 bf16;
typedef __attribute__((ext_vector_type(8))) short bf16x8;
typedef __attribute__((ext_vector_type(4))) float f32x4;

__device__ __forceinline__ float b2f(bf16 x){ return __bfloat162float(x); }
__device__ __forceinline__ bf16  f2b(float x){ return __float2bfloat16(x); }
__device__ __forceinline__ unsigned short b2u(bf16 x){ union{bf16 b; unsigned short u;} c; c.b = x; return c.u; }

#define LOG2E 1.4426950408889634f
#define QSC (0.17677669529663687f * LOG2E)

#define GLD16(gp, lp) __builtin_amdgcn_global_load_lds( \
    (const __attribute__((address_space(1))) void*)(gp), \
    (__attribute__((address_space(3))) void*)(lp), 16, 0, 0)

__device__ __forceinline__ float fexp2(float x){       // v_exp_f32 = 2^x, ~1 ulp
  float r; asm("v_exp_f32 %0, %1" : "=v"(r) : "v"(x)); return r;
}
__device__ __forceinline__ float fast_exp(float x){ return fexp2(x * LOG2E); }
__device__ __forceinline__ float eluf(float x){ return x > 0.f ? x : fast_exp(x) - 1.f; }
__device__ __forceinline__ float fast_tanh(float x){
  float cx = fminf(fmaxf(x, -15.f), 15.f);
  float t = fexp2(cx * (2.f*LOG2E));
  return (t - 1.f) / (t + 1.f);
}

#define PE_C (-0.07195578415606394f)  /* -ln(10000)/128 */

__device__ __forceinline__ float pe_val(int pos, int d){
  int j2 = d & ~1;
  float ang = (float)pos * expf((float)j2 * PE_C);
  return (d & 1) ? cosf(ang) : sinf(ang);
}

// ---------------- merged prep: embedding + 7 weight packs + PE table + q-prep ----------------
__device__ __forceinline__ void pack_one(const float* __restrict__ W, bf16* __restrict__ out,
                                         int K, int N, int conv, int qscale, int t){
  int j = t & 7, lane = (t >> 3) & 63;
  int rest = t >> 9; int NT = N >> 4;
  int nt = rest % NT; int kb = rest / NT;
  int k = kb*32 + ((lane >> 4) << 3) + j;
  int n = nt*16 + (lane & 15);
  float v = conv ? W[n*384 + (k & 127)*3 + (k >> 7)] : W[(long)n*K + k];
  if (qscale && n < 128) v *= QSC;
  out[t] = f2b(v);
}

__global__ void k_prep(const int* __restrict__ tok, const float* __restrict__ tab,
                       const float* __restrict__ w_ce, const float* __restrict__ w_ct,
                       const float* __restrict__ w_cg, const float* __restrict__ w_ces,
                       const float* __restrict__ w_cts, const float* __restrict__ wi,
                       const float* __restrict__ wo, const float* __restrict__ bi,
                       const float* __restrict__ t1, const float* __restrict__ t2,
                       bf16* P_CE, bf16* P_CT, bf16* P_CG, bf16* P_CES, bf16* P_CTS,
                       bf16* P_WI, bf16* P_WO, float* __restrict__ pet,
                       bf16* __restrict__ emb, float* __restrict__ rkv){
  int bid = blockIdx.x;
  if (bid < 8192){
    // embedding + PE (computed inline; PET table written by later blocks is not used here)
    int t = bid*256 + threadIdx.x;             // < 2097152
    int q = t & 15;
    int flat = t >> 4; int w = flat & 127;
    int tk = tok[flat];
    const float* ta = tab + tk*128 + q*8;
    bf16 ob[8];
    #pragma unroll
    for (int i = 0; i < 8; ++i) ob[i] = f2b(ta[i] + pe_val(w, q*8 + i));
    *(f32x4*)(emb + (size_t)t*8) = *(f32x4*)ob;
    return;
  }
  bid -= 8192;
  if (bid < 1152){
    int grp = bid / 192; int t = (bid % 192)*256 + threadIdx.x;
    const float* W; bf16* out; int K, N, conv, qs = 0;
    if      (grp == 0){ W = w_ce;  out = P_CE;  K=384; N=128; conv=1; }
    else if (grp == 1){ W = w_ct;  out = P_CT;  K=384; N=128; conv=1; }
    else if (grp == 2){ W = w_cg;  out = P_CG;  K=384; N=128; conv=1; }
    else if (grp == 3){ W = w_ces; out = P_CES; K=384; N=128; conv=1; }
    else if (grp == 4){ W = w_cts; out = P_CTS; K=384; N=128; conv=1; }
    else              { W = wi;    out = P_WI;  K=128; N=384; conv=0; qs=1; }
    pack_one(W, out, K, N, conv, qs, t);
  } else if (bid < 1216){
    int t = (bid - 1152)*256 + threadIdx.x;
    pack_one(wo, P_WO, 128, 128, 0, 0, t);
  } else if (bid < 1280){
    int i = (bid - 1216)*256 + threadIdx.x;
    if (i < 16384) pet[i] = pe_val(i >> 7, i & 127);
  } else {
    // q-prep: qp = tgt@Wq^T+bq ; rk[which][h][i] = sum_d qp[h*32+d]*Wk[h*32+d][i]
    int tid = threadIdx.x;
    __shared__ float qps[256];
    {
      int which = tid >> 7, jj = tid & 127;
      const float* t = which ? t2 : t1;
      float a = bi[jj];
      for (int i = 0; i < 128; ++i) a += wi[jj*128 + i] * t[i];
      qps[tid] = a;
    }
    __syncthreads();
    int i = tid & 127, which = tid >> 7;
    for (int h = 0; h < 4; ++h){
      float a = 0.f;
      for (int d = 0; d < 32; ++d) a += qps[which*128 + h*32 + d] * wi[(128 + h*32 + d)*128 + i];
      rkv[which*512 + h*128 + i] = a;
    }
  }
}

__global__ void k_se(const bf16* __restrict__ in, const float* __restrict__ pet, bf16* __restrict__ out){
  int idx = blockIdx.x*256 + threadIdx.x;      // < 131072
  int d = idx & 127; int n = (idx >> 7) & 63;
  out[idx] = f2b(b2f(in[idx]) + pet[(n << 7) + d]);
}

// ---------------- MFMA GEMM, double-buffered 1-barrier pipeline ----------------
// GLL=true: async global_load_lds staging (linear LDS dest, inverse-swizzled per-lane source).
// GLL=false: reg-staged path (supports fused LayerNorm on A load).
template<bool GLL>
__global__ __launch_bounds__(256)
void k_gemm_mfma(const bf16* __restrict__ A, const bf16* __restrict__ Bp_, const bf16* __restrict__ Bp2,
                 const float* __restrict__ bias_, const float* __restrict__ bias2,
                 bf16* __restrict__ C_, bf16* __restrict__ C2p,
                 const bf16* __restrict__ mul,
                 int M, int K, int a_lout, int a_lind, int lda,
                 int NT, int n0t, int ldc, int act_, int act2,
                 const float* __restrict__ lnst, int lngrp){
  const bf16* Bp = Bp_; const float* bias = bias_; bf16* C = C_; int act = act_;
  if (blockIdx.z){ Bp = Bp2; bias = bias2; C = C2p; act = act2; }

  __shared__ f32x4 AsV[2][512];                 // 2 x 8 KB
  char* As0 = (char*)AsV[0];
  char* As1 = (char*)AsV[1];
  int tid = threadIdx.x;
  int lane = tid & 63, wave = tid >> 6;
  int wm = wave >> 1, wn = wave & 1;
  int m0 = blockIdx.x*128;
  int by = blockIdx.y;

  long offA[2]; bool okA[2]; float lnm[2], lnr[2]; int sbyte[2];
  #pragma unroll
  for (int p = 0; p < 2; ++p){
    int e = tid + p*256;
    int row, kq;
    if (GLL){
      // inverse of slot swizzle: slot x holds (row,kq) with x = (row<<2|kq) ^ (row&7)
      int x = e;
      row = (((x >> 3) << 1) | (((x >> 2) ^ (x >> 4)) & 1)) & 127;
      kq  = ((((x >> 1) ^ (x >> 3)) & 1) << 1) | ((x ^ (x >> 2) ^ (x >> 4)) & 1);
    } else {
      row = e >> 2; kq = e & 3;
    }
    int m = m0 + row;
    okA[p] = (m < M);
    long off = 0;
    if (okA[p]){
      off = (a_lout > 0) ? (long)(m / a_lout)*a_lind + (long)(m % a_lout)*128 + kq*8
                         : (long)m*lda + kq*8;
    }
    offA[p] = off;
    lnm[p] = 0.f; lnr[p] = 1.f;
    if (!GLL && lnst && okA[p]){ int g = (int)(off / (long)lngrp); lnm[p] = lnst[2*g]; lnr[p] = lnst[2*g+1]; }
    sbyte[p] = (row*64 + kq*16) ^ ((row & 7) << 4);
  }

  const bf16* bptr[4];
  size_t bstep = (size_t)NT*512;
  #pragma unroll
  for (int fn = 0; fn < 4; ++fn){
    int ntile = n0t + by*8 + wn*4 + fn;
    bptr[fn] = Bp + ((size_t)ntile*64 + lane)*8;
  }
  int abyte[4];
  #pragma unroll
  for (int fm = 0; fm < 4; ++fm){
    int row = wm*64 + fm*16 + (lane & 15);
    abyte[fm] = (row*64 + ((lane >> 4) << 4)) ^ ((row & 7) << 4);
  }

  f32x4 acc[4][4];
  #pragma unroll
  for (int i = 0; i < 4; ++i)
    #pragma unroll
    for (int j = 0; j < 4; ++j) acc[i][j] = (f32x4){0.f,0.f,0.f,0.f};

  int nk = K >> 5;

  if constexpr (GLL){
    int ldsw = (tid >> 6)*1024;
    #pragma unroll
    for (int p = 0; p < 2; ++p)
      GLD16(A + offA[p], As0 + p*4096 + ldsw);
    __syncthreads();
    for (int kb = 0; kb < nk; ++kb){
      char* cur = (kb & 1) ? As1 : As0;
      char* nxt = (kb & 1) ? As0 : As1;
      bool more = (kb + 1) < nk;
      if (more){
        #pragma unroll
        for (int p = 0; p < 2; ++p)
          GLD16(A + offA[p] + (kb+1)*32, nxt + p*4096 + ldsw);
      }
      bf16x8 bfr[4];
      #pragma unroll
      for (int fn = 0; fn < 4; ++fn) bfr[fn] = *(const bf16x8*)(bptr[fn] + (size_t)kb*bstep);
      bf16x8 afr[4];
      #pragma unroll
      for (int fm = 0; fm < 4; ++fm) afr[fm] = *(const bf16x8*)(cur + abyte[fm]);
      #pragma unroll
      for (int fm = 0; fm < 4; ++fm)
        #pragma unroll
        for (int fn = 0; fn < 4; ++fn)
          acc[fm][fn] = __builtin_amdgcn_mfma_f32_16x16x32_bf16(afr[fm], bfr[fn], acc[fm][fn], 0, 0, 0);
      __syncthreads();
    }
  } else {
    auto loadA = [&](int p, int kb)->float4{
      float4 v = make_float4(0.f,0.f,0.f,0.f);
      if (okA[p]){
        v = *(const float4*)(A + offA[p] + kb*32);
        if (lnst){
          bf16* pp = (bf16*)&v; bf16 oo[8];
          #pragma unroll
          for (int u = 0; u < 8; ++u) oo[u] = f2b((b2f(pp[u]) - lnm[p]) * lnr[p]);
          v = *(float4*)&oo[0];
        }
      }
      return v;
    };
    float4 va0 = loadA(0, 0), va1 = loadA(1, 0);
    *(float4*)(As0 + sbyte[0]) = va0;
    *(float4*)(As0 + sbyte[1]) = va1;
    __syncthreads();
    for (int kb = 0; kb < nk; ++kb){
      char* cur = (kb & 1) ? As1 : As0;
      char* nxt = (kb & 1) ? As0 : As1;
      bool more = (kb + 1) < nk;
      if (more){ va0 = loadA(0, kb+1); va1 = loadA(1, kb+1); }  // issue early
      bf16x8 bfr[4];
      #pragma unroll
      for (int fn = 0; fn < 4; ++fn) bfr[fn] = *(const bf16x8*)(bptr[fn] + (size_t)kb*bstep);
      bf16x8 afr[4];
      #pragma unroll
      for (int fm = 0; fm < 4; ++fm) afr[fm] = *(const bf16x8*)(cur + abyte[fm]);
      #pragma unroll
      for (int fm = 0; fm < 4; ++fm)
        #pragma unroll
        for (int fn = 0; fn < 4; ++fn)
          acc[fm][fn] = __builtin_amdgcn_mfma_f32_16x16x32_bf16(afr[fm], bfr[fn], acc[fm][fn], 0, 0, 0);
      if (more){
        *(float4*)(nxt + sbyte[0]) = va0;   // write late
        *(float4*)(nxt + sbyte[1]) = va1;
      }
      __syncthreads();
    }
  }

  #pragma unroll
  for (int fm = 0; fm < 4; ++fm){
    #pragma unroll
    for (int r = 0; r < 4; ++r){
      int m = m0 + wm*64 + fm*16 + ((lane >> 4) << 2) + r;
      if (m >= M) continue;
      #pragma unroll
      for (int fn = 0; fn < 4; ++fn){
        int n = by*128 + wn*64 + fn*16 + (lane & 15);
        float v = acc[fm][fn][r] + (bias ? bias[n] : 0.f);
        if (act == 1) v = eluf(v);
        else if (act == 2) v = fast_tanh(v);
        if (mul) v *= b2f(mul[(long)m*ldc + n]);
        C[(long)m*ldc + n] = f2b(v);
      }
    }
  }
}

// ---------------- fused QKV-projection + MFMA self-attention ----------------
// Two independent branches merged into one dispatch: blocks >= nhalf use (X2, o2).
template<int L>
__global__ __launch_bounds__(256)
void k_attn_fused(const bf16* __restrict__ X, const bf16* __restrict__ X2,
                  const bf16* __restrict__ Pwi, const float* __restrict__ bi,
                  bf16* __restrict__ o, bf16* __restrict__ o2, int nhalf){
  constexpr int KB  = (L + 31) / 32;   // PV K-steps
  constexpr int MT  = KB * 2;          // 16-row tiles
  constexpr int WMT = MT / 4;          // M-tiles per wave
  constexpr int NP  = KB * 32;         // padded seq len
  constexpr int PRS = NP * 2;          // P row stride bytes

  __shared__ alignas(16) char As[NP*256];   // X tile; aliased by Pb
  __shared__ alignas(16) char Qb[NP*64];
  __shared__ alignas(16) char Kb[NP*64];
  __shared__ alignas(16) char Vt[32*PRS];
  char* Pb = As;

  int tid = threadIdx.x;
  int bid = blockIdx.x;
  const bf16* Xp = X; bf16* op = o;
  if (bid >= nhalf){ Xp = X2; op = o2; bid -= nhalf; }
  int s = bid >> 2, h = bid & 3;
  const bf16* xb = Xp + (size_t)s*L*128;

  {
    constexpr int NCH = (NP*16)/256;
    int ldsw = (tid >> 6)*1024;
    #pragma unroll
    for (int p = 0; p < NCH; ++p){
      int x = p*256 + tid;
      int row = x >> 4;
      int c = (x & 15) ^ (row & 7);
      const bf16* gp = (row < L) ? (xb + (size_t)row*128 + c*8) : xb;
      GLD16(gp, As + p*4096 + ldsw);
    }
  }
  __syncthreads();

  int lane = tid & 63, wave = tid >> 6;
  int col = lane & 15;

  // ---- projection ----
  __builtin_amdgcn_s_setprio(1);
  #pragma unroll
  for (int mt = 0; mt < WMT; ++mt){
    int mtile = wave*WMT + mt;
    int arow = mtile*16 + col;
    bf16x8 a4[4];
    #pragma unroll
    for (int kb = 0; kb < 4; ++kb)
      a4[kb] = *(const bf16x8*)(As + ((arow*256 + kb*64 + ((lane >> 4) << 4)) ^ ((arow & 7) << 4)));
    #pragma unroll
    for (int which = 0; which < 3; ++which){
      f32x4 av[2];
      #pragma unroll
      for (int nt = 0; nt < 2; ++nt){
        int ntile = which*8 + h*2 + nt;
        float bia = bi[which*128 + h*32 + nt*16 + col];
        if (which == 0) bia *= QSC;
        av[nt] = (f32x4){bia, bia, bia, bia};
        #pragma unroll
        for (int kb = 0; kb < 4; ++kb){
          bf16x8 bfr = *(const bf16x8*)(Pwi + (((size_t)kb*24 + ntile)*64 + lane)*8);
          av[nt] = __builtin_amdgcn_mfma_f32_16x16x32_bf16(a4[kb], bfr, av[nt], 0, 0, 0);
        }
      }
      #pragma unroll
      for (int r = 0; r < 4; ++r){
        int row = mtile*16 + ((lane >> 4) << 2) + r;
        if (which < 2){
          unsigned pk = (unsigned)b2u(f2b(av[0][r])) | ((unsigned)b2u(f2b(av[1][r])) << 16);
          char* dst = which ? Kb : Qb;
          *(unsigned*)(dst + ((row*64 + col*4) ^ ((row & 7) << 4))) = pk;
        } else {
          int pos = (row & 15)*MT + (row >> 4);
          #pragma unroll
          for (int nt = 0; nt < 2; ++nt){
            int d = nt*16 + col;
            *(bf16*)(Vt + ((d*PRS + pos*2) ^ ((d & 7) << 4))) = f2b(av[nt][r]);
          }
        }
      }
    }
  }
  __builtin_amdgcn_s_setprio(0);
  __syncthreads();

  // ---- QK^T (scores in log2 units) ----
  f32x4 acc[WMT][MT];
  #pragma unroll
  for (int mt = 0; mt < WMT; ++mt)
    #pragma unroll
    for (int nt = 0; nt < MT; ++nt) acc[mt][nt] = (f32x4){0.f,0.f,0.f,0.f};

  bf16x8 af[WMT];
  #pragma unroll
  for (int mt = 0; mt < WMT; ++mt){
    int row = (wave*WMT + mt)*16 + col;
    af[mt] = *(const bf16x8*)(Qb + ((row*64 + ((lane >> 4) << 4)) ^ ((row & 7) << 4)));
  }
  __builtin_amdgcn_s_setprio(1);
  #pragma unroll
  for (int nt = 0; nt < MT; ++nt){
    int rk2 = nt*16 + col;
    bf16x8 bfk = *(const bf16x8*)(Kb + ((rk2*64 + ((lane >> 4) << 4)) ^ ((rk2 & 7) << 4)));
    #pragma unroll
    for (int mt = 0; mt < WMT; ++mt)
      acc[mt][nt] = __builtin_amdgcn_mfma_f32_16x16x32_bf16(af[mt], bfk, acc[mt][nt], 0, 0, 0);
  }
  __builtin_amdgcn_s_setprio(0);

  // ---- softmax: mask last col-tile, single v_exp, packed P write, deferred normalize ----
  const bool lastMask = col >= (L - (MT-1)*16);
  float pinv[WMT][4];
  #pragma unroll
  for (int mt = 0; mt < WMT; ++mt){
    #pragma unroll
    for (int r = 0; r < 4; ++r){
      float mx = -1e30f;
      #pragma unroll
      for (int nt = 0; nt < MT; ++nt){
        float v = acc[mt][nt][r];
        if (nt == MT-1 && lastMask){ v = -1e30f; acc[mt][nt][r] = v; }
        mx = fmaxf(mx, v);
      }
      mx = fmaxf(mx, __shfl_xor(mx, 1));
      mx = fmaxf(mx, __shfl_xor(mx, 2));
      mx = fmaxf(mx, __shfl_xor(mx, 4));
      mx = fmaxf(mx, __shfl_xor(mx, 8));
      float sum = 0.f;
      bf16 prow[MT];
      #pragma unroll
      for (int nt = 0; nt < MT; ++nt){
        float p = fexp2(acc[mt][nt][r] - mx);
        prow[nt] = f2b(p);
        sum += p;
      }
      sum += __shfl_xor(sum, 1);
      sum += __shfl_xor(sum, 2);
      sum += __shfl_xor(sum, 4);
      sum += __shfl_xor(sum, 8);
      pinv[mt][r] = 1.f / sum;
      int row = (wave*WMT + mt)*16 + ((lane >> 4) << 2) + r;
      char* dst = Pb + ((row*PRS + col*(MT*2)) ^ ((row & 7) << 4));
      if constexpr (MT == 8) *(f32x4*)dst = *(f32x4*)prow;
      else                   *(float2*)dst = *(float2*)prow;
    }
  }

  // ---- PV (same-wave rows; no barrier), normalize at output ----
  #pragma unroll
  for (int mt = 0; mt < WMT; ++mt){
    int mtile = wave*WMT + mt;
    f32x4 o0 = (f32x4){0.f,0.f,0.f,0.f}, o1 = (f32x4){0.f,0.f,0.f,0.f};
    __builtin_amdgcn_s_setprio(1);
    #pragma unroll
    for (int kb = 0; kb < KB; ++kb){
      int row = mtile*16 + col;
      bf16x8 pa = *(const bf16x8*)(Pb + ((row*PRS + kb*64 + ((lane >> 4) << 4)) ^ ((row & 7) << 4)));
      int d0 = col;
      bf16x8 v0 = *(const bf16x8*)(Vt + ((d0*PRS + kb*64 + ((lane >> 4) << 4)) ^ ((d0 & 7) << 4)));
      bf16x8 v1 = *(const bf16x8*)(Vt + (((d0+16)*PRS + kb*64 + ((lane >> 4) << 4)) ^ (((d0+16) & 7) << 4)));
      o0 = __builtin_amdgcn_mfma_f32_16x16x32_bf16(pa, v0, o0, 0, 0, 0);
      o1 = __builtin_amdgcn_mfma_f32_16x16x32_bf16(pa, v1, o1, 0, 0, 0);
    }
    __builtin_amdgcn_s_setprio(0);
    #pragma unroll
    for (int r = 0; r < 4; ++r){
      int row = mtile*16 + ((lane >> 4) << 2) + r;
      if (row < L){
        size_t ob = ((size_t)s*L + row)*128 + h*32 + col;
        op[ob]      = f2b(o0[r] * pinv[mt][r]);
        op[ob + 16] = f2b(o1[r] * pinv[mt][r]);
      }
    }
  }
}

// ---------------- fused target-query attention ----------------
template<int L>
__global__ __launch_bounds__(256)
void k_attn_tgt(const bf16* __restrict__ hin, const float* __restrict__ rk,
                const float* __restrict__ wi, const float* __restrict__ bi,
                bf16* __restrict__ outp){
  __shared__ alignas(16) char Hs[L*256];
  __shared__ float RKs[512];
  __shared__ float Ps[512];
  __shared__ float Cs[512];
  int tid = threadIdx.x, lane = tid & 63, wave = tid >> 6;
  int s = blockIdx.x;
  const bf16* hb = hin + (size_t)s*L*128;
  for (int e = tid; e < L*16; e += 256){
    int row = e >> 4, c = e & 15;
    *(float4*)(Hs + row*256 + ((c ^ (row & 7)) << 4)) = *(const float4*)(hb + row*128 + c*8);
  }
  for (int e = tid; e < 512; e += 256) RKs[e] = rk[e];
  __syncthreads();

  int j0 = lane, j1 = lane + 64;
  float v0 = -1e30f, v1 = -1e30f;
  if (j0 < L){
    float a = 0.f;
    #pragma unroll
    for (int c = 0; c < 16; ++c){
      bf16x8 x = *(const bf16x8*)(Hs + j0*256 + ((c ^ (j0 & 7)) << 4));
      #pragma unroll
      for (int u = 0; u < 8; ++u) a += b2f(((bf16*)&x)[u]) * RKs[wave*128 + c*8 + u];
    }
    v0 = a * 0.17677669529663687f;
  }
  if (j1 < L){
    float a = 0.f;
    #pragma unroll
    for (int c = 0; c < 16; ++c){
      bf16x8 x = *(const bf16x8*)(Hs + j1*256 + ((c ^ (j1 & 7)) << 4));
      #pragma unroll
      for (int u = 0; u < 8; ++u) a += b2f(((bf16*)&x)[u]) * RKs[wave*128 + c*8 + u];
    }
    v1 = a * 0.17677669529663687f;
  }
  float mx = fmaxf(v0, v1);
  #pragma unroll
  for (int off = 32; off; off >>= 1) mx = fmaxf(mx, __shfl_xor(mx, off));
  float e0 = (j0 < L) ? fast_exp(v0 - mx) : 0.f;
  float e1 = (j1 < L) ? fast_exp(v1 - mx) : 0.f;
  float sum = e0 + e1;
  #pragma unroll
  for (int off = 32; off; off >>= 1) sum += __shfl_xor(sum, off);
  float inv = 1.f / sum;
  Ps[wave*128 + j0] = e0 * inv;
  Ps[wave*128 + j1] = e1 * inv;

  int i0 = lane*2;
  float c0 = 0.f, c1 = 0.f;
  for (int j = 0; j < L; ++j){
    float p = Ps[wave*128 + j];
    short2 w2 = *(const short2*)(Hs + j*256 + (((i0 >> 3) ^ (j & 7)) << 4) + (i0 & 7)*2);
    c0 += p * b2f(*(bf16*)&w2.x);
    c1 += p * b2f(*(bf16*)&w2.y);
  }
  Cs[wave*128 + i0]     = c0;
  Cs[wave*128 + i0 + 1] = c1;
  __syncthreads();

  if (tid < 128){
    int h2 = tid >> 5;
    float a = bi[256 + tid];
    const float* wr = wi + (size_t)(256 + tid)*128;
    for (int i = 0; i < 128; ++i) a += wr[i] * Cs[h2*128 + i];
    outp[(size_t)s*128 + tid] = f2b(a);
  }
}

// ---------------- big LayerNorm stats: partial / finalize ----------------
__global__ void k_ln_partial(const bf16* __restrict__ x, float* __restrict__ part, int GS, int P){
  int pi = blockIdx.x % P;
  int chunk8 = GS / P / 8;
  size_t base = (size_t)(blockIdx.x / P)*GS + (size_t)pi*(GS/P);
  float s = 0.f, s2 = 0.f;
  for (int i = threadIdx.x; i < chunk8; i += 256){
    f32x4 raw = *(const f32x4*)(x + base + (size_t)i*8);
    const bf16* xb = (const bf16*)&raw;
    #pragma unroll
    for (int j = 0; j < 8; ++j){ float v = b2f(xb[j]); s += v; s2 += v*v; }
  }
  #pragma unroll
  for (int off = 32; off; off >>= 1){ s += __shfl_xor(s, off); s2 += __shfl_xor(s2, off); }
  __shared__ float sh[8];
  int lane = threadIdx.x & 63, wv = threadIdx.x >> 6;
  if (lane == 0){ sh[wv] = s; sh[4 + wv] = s2; }
  __syncthreads();
  if (threadIdx.x == 0){
    part[blockIdx.x*2]     = sh[0]+sh[1]+sh[2]+sh[3];
    part[blockIdx.x*2 + 1] = sh[4]+sh[5]+sh[6]+sh[7];
  }
}

__global__ void k_ln_fin(const float* __restrict__ part, float* __restrict__ stats, int P, int GS){
  int g = blockIdx.x;
  float s = 0.f, s2 = 0.f;
  for (int i = threadIdx.x; i < P; i += 256){ s += part[(g*P + i)*2]; s2 += part[(g*P + i)*2 + 1]; }
  #pragma unroll
  for (int off = 32; off; off >>= 1){ s += __shfl_xor(s, off); s2 += __shfl_xor(s2, off); }
  __shared__ float sh[8];
  int lane = threadIdx.x & 63, wv = threadIdx.x >> 6;
  if (lane == 0){ sh[wv] = s; sh[4 + wv] = s2; }
  __syncthreads();
  if (threadIdx.x == 0){
    float S = sh[0]+sh[1]+sh[2]+sh[3], S2 = sh[4]+sh[5]+sh[6]+sh[7];
    float mean = S / GS;
    float var = S2 / GS - mean*mean;
    stats[g*2] = mean; stats[g*2 + 1] = rsqrtf(var + 1e-5f);
  }
}

// ---------------- small LN (bf16), one block per group ----------------
__global__ void k_ln_small_bf16(const bf16* __restrict__ x, bf16* __restrict__ y, int n){
  int g = blockIdx.x;
  const bf16* xb = x + (size_t)g*n;
  bf16* yb = y + (size_t)g*n;
  float s = 0.f, s2 = 0.f;
  for (int i = threadIdx.x; i < n; i += 256){ float v = b2f(xb[i]); s += v; s2 += v*v; }
  #pragma unroll
  for (int off = 32; off; off >>= 1){ s += __shfl_xor(s, off); s2 += __shfl_xor(s2, off); }
  __shared__ float sh[8];  __shared__ float ms[2];
  int lane = threadIdx.x & 63, wv = threadIdx.x >> 6;
  if (lane == 0){ sh[wv] = s; sh[4 + wv] = s2; }
  __syncthreads();
  if (threadIdx.x == 0){
    float S = sh[0]+sh[1]+sh[2]+sh[3], S2 = sh[4]+sh[5]+sh[6]+sh[7];
    float mean = S / n;
    ms[0] = mean; ms[1] = rsqrtf(S2 / n - mean*mean + 1e-5f);
  }
  __syncthreads();
  float mean = ms[0], inv = ms[1];
  for (int i = threadIdx.x; i < n; i += 256) yb[i] = f2b((b2f(xb[i]) - mean)*inv);
}

// ---------------- small LN (f32), one block per group ----------------
__global__ void k_ln_small_f32(const float* __restrict__ x, float* __restrict__ y, int n, int act){
  int g = blockIdx.x;
  const float* xb = x + (size_t)g*n;
  float* yb = y + (size_t)g*n;
  float s = 0.f, s2 = 0.f;
  for (int i = threadIdx.x; i < n; i += 256){ float v = xb[i]; s += v; s2 += v*v; }
  #pragma unroll
  for (int off = 32; off; off >>= 1){ s += __shfl_xor(s, off); s2 += __shfl_xor(s2, off); }
  __shared__ float sh[8];  __shared__ float ms[2];
  int lane = threadIdx.x & 63, wv = threadIdx.x >> 6;
  if (lane == 0){ sh[wv] = s; sh[4 + wv] = s2; }
  __syncthreads();
  if (threadIdx.x == 0){
    float S = sh[0]+sh[1]+sh[2]+sh[3], S2 = sh[4]+sh[5]+sh[6]+sh[7];
    float mean = S / n;
    ms[0] = mean; ms[1] = rsqrtf(S2 / n - mean*mean + 1e-5f);
  }
  __syncthreads();
  float mean = ms[0], inv = ms[1];
  for (int i = threadIdx.x; i < n; i += 256){
    float v = (xb[i] - mean)*inv;
    if (act == 1) v = eluf(v);
    else if (act == 3) v = 1.f/(1.f + fast_exp(-v));
    yb[i] = v;
  }
}

// ---------------- decoder stage A (tiny front chain), one block per b ----------------
__global__ __launch_bounds__(256)
void k_dec_a(const bf16* __restrict__ DOC,
             const float* __restrict__ w_mu, const float* __restrict__ b_mu,
             const float* __restrict__ w_lv, const float* __restrict__ b_lv,
             const float* __restrict__ eps,
             const float* __restrict__ w_di, const float* __restrict__ b_di,
             const float* __restrict__ dk_w, const float* __restrict__ dk_b,
             const float* __restrict__ dv_w, const float* __restrict__ dv_b,
             const float* __restrict__ wt1, const float* __restrict__ bt1,
             float* __restrict__ dout, float* __restrict__ DEC2){
  int b = blockIdx.x, tid = threadIdx.x;
  __shared__ float Zs[128], H3[128], KD[128], VD[128], D1[128];
  __shared__ float C1[448];
  __shared__ float sc[64];
  __shared__ float red[8], ms[2];

  if (tid < 128){
    const bf16* dr = DOC + b*128;
    float mu = b_mu[tid], lv = b_lv[tid];
    for (int i = 0; i < 128; ++i){
      float x = b2f(dr[i]);
      mu += x * w_mu[tid*128 + i];
      lv += x * w_lv[tid*128 + i];
    }
    dout[26624 + b*128 + tid] = mu;
    dout[28672 + b*128 + tid] = lv;
    Zs[tid] = mu + eps[b*128 + tid] * fast_exp(0.5f*lv);
  }
  __syncthreads();
  if (tid < 128){
    float a = b_di[tid];
    for (int i = 0; i < 128; ++i) a += Zs[i] * w_di[tid*128 + i];
    H3[tid] = a;
  }
  __syncthreads();
  if (tid < 128){
    int l = tid & 3, o2 = tid >> 2;
    float ak = dk_b[o2], av = dv_b[o2];
    for (int i = 0; i < 32; ++i){
      float xv = H3[i*4 + l];
      ak += dk_w[o2*32 + i]*xv;
      av += dv_w[o2*32 + i]*xv;
    }
    KD[tid] = ak; VD[tid] = av;
  }
  __syncthreads();
  if (tid < 64){
    int h = tid >> 4, l = (tid >> 2) & 3, m = tid & 3;
    float a = 0.f;
    #pragma unroll
    for (int d = 0; d < 8; ++d) a += KD[(h*8+d)*4 + l] * VD[(h*8+d)*4 + m];
    sc[tid] = a * 0.35355339059327373f;
  }
  __syncthreads();
  if (tid < 16){
    int base = tid*4;
    float mx = fmaxf(fmaxf(sc[base],sc[base+1]),fmaxf(sc[base+2],sc[base+3]));
    float e0=fast_exp(sc[base]-mx), e1=fast_exp(sc[base+1]-mx), e2=fast_exp(sc[base+2]-mx), e3=fast_exp(sc[base+3]-mx);
    float inv = 1.f/(e0+e1+e2+e3);
    sc[base]=e0*inv; sc[base+1]=e1*inv; sc[base+2]=e2*inv; sc[base+3]=e3*inv;
  }
  __syncthreads();
  if (tid < 128){
    int h = tid >> 5, rem = tid & 31, l = rem >> 3, d = rem & 7;
    float a = 0.f;
    #pragma unroll
    for (int m = 0; m < 4; ++m) a += sc[h*16 + l*4 + m] * VD[(h*8+d)*4 + m];
    D1[tid] = eluf(a);
  }
  __syncthreads();
  for (int idx = tid; idx < 448; idx += 256){
    int co = idx / 7, lo = idx % 7;
    float a = bt1[co];
    for (int k = 0; k < 3; ++k){
      int t = lo + 1 - k;
      if (t < 0 || (t & 1)) continue;
      int li = t >> 1; if (li >= 4) continue;
      float aa = 0.f;
      for (int ci = 0; ci < 32; ++ci) aa += D1[ci*4 + li] * wt1[ci*192 + co*3 + k];
      a += aa;
    }
    C1[idx] = a;
  }
  __syncthreads();
  {
    float s = 0.f, s2 = 0.f;
    for (int i = tid; i < 448; i += 256){ float v = C1[i]; s += v; s2 += v*v; }
    #pragma unroll
    for (int o = 32; o; o >>= 1){ s += __shfl_xor(s, o); s2 += __shfl_xor(s2, o); }
    int lane = tid & 63, wv = tid >> 6;
    if (lane == 0){ red[wv] = s; red[4+wv] = s2; }
    __syncthreads();
    if (tid == 0){
      float S = red[0]+red[1]+red[2]+red[3], S2 = red[4]+red[5]+red[6]+red[7];
      float mean = S/448.f; ms[0] = mean; ms[1] = rsqrtf(S2/448.f - mean*mean + 1e-5f);
    }
    __syncthreads();
    float mean = ms[0], inv = ms[1];
    for (int i = tid; i < 448; i += 256)
      DEC2[b*448 + i] = eluf((C1[i]-mean)*inv);
  }
}

// three channel-projections sharing one input read
__global__ void k_chanproj3(const float* __restrict__ x,
                            const float* __restrict__ w1, const float* __restrict__ b1,
                            const float* __restrict__ w2, const float* __restrict__ b2,
                            const float* __restrict__ w3, const float* __restrict__ b3,
                            float* __restrict__ y1, float* __restrict__ y2, float* __restrict__ y3,
                            int Bn, int C, int L){
  int idx = blockIdx.x*256 + threadIdx.x;
  if (idx >= Bn*C*L) return;
  int l = idx % L; int t2 = idx / L; int o = t2 % C; int b = t2 / C;
  float a1 = b1[o], a2 = b2[o], a3 = b3[o];
  const float* xb = x + (size_t)b*C*L + l;
  for (int i = 0; i < C; ++i){
    float xv = xb[i*L];
    a1 += w1[(size_t)o*C + i]*xv;
    a2 += w2[(size_t)o*C + i]*xv;
    a3 += w3[(size_t)o*C + i]*xv;
  }
  y1[idx] = a1; y2[idx] = a2; y3[idx] = a3;
}

__global__ __launch_bounds__(256)
void k_dec_attn2(const float* __restrict__ qc, const float* __restrict__ kc,
                 const float* __restrict__ vc, float* __restrict__ out){
  int b = blockIdx.x >> 2, h = blockIdx.x & 3, tid = threadIdx.x;
  __shared__ float sc[169];
  const float* qb = qc + b*1664 + h*416;
  const float* kb = kc + b*1664 + h*416;
  const float* vb = vc + b*1664 + h*416;
  if (tid < 169){
    int l = tid/13, m = tid - l*13;
    float a = 0.f;
    #pragma unroll
    for (int d = 0; d < 32; ++d) a += qb[d*13 + l] * kb[d*13 + m];
    sc[tid] = a * 0.17677669529663687f;
  }
  __syncthreads();
  if (tid < 13){
    float mx = -1e30f;
    for (int m = 0; m < 13; ++m) mx = fmaxf(mx, sc[tid*13 + m]);
    float s = 0.f;
    for (int m = 0; m < 13; ++m){ float p = fast_exp(sc[tid*13 + m] - mx); sc[tid*13 + m] = p; s += p; }
    float inv = 1.f/s;
    for (int m = 0; m < 13; ++m) sc[tid*13 + m] *= inv;
  }
  __syncthreads();
  for (int idx = tid; idx < 416; idx += 256){
    int l = idx >> 5, d = idx & 31;
    float a = 0.f;
    for (int m = 0; m < 13; ++m) a += sc[l*13 + m] * vb[m*32 + d];
    out[b*1664 + h*416 + idx] = eluf(a);
  }
}

// ConvTranspose1d (K=3), x staged in LDS
__global__ __launch_bounds__(256)
void k_convt(const float* __restrict__ x, const float* __restrict__ w,
             const float* __restrict__ bias, float* __restrict__ y,
             int Bn, int Ci, int Co, int Lin, int Lout, int stride, int pad, int nch){
  __shared__ float xs[1664];
  int b = blockIdx.x / nch;
  int c0 = (blockIdx.x % nch)*16;
  int tid = threadIdx.x;
  for (int i = tid; i < Ci*Lin; i += 256) xs[i] = x[(size_t)b*Ci*Lin + i];
  __syncthreads();
  int co = c0 + (tid & 15);
  int lo = tid >> 4;
  if (co >= Co || lo >= Lout) return;
  float a = bias[co];
  for (int k = 0; k < 3; ++k){
    int t = lo + pad - k;
    if (t < 0 || (t % stride)) continue;
    int li = t / stride;
    if (li >= Lin) continue;
    float aa = 0.f;
    for (int ci = 0; ci < Ci; ++ci) aa += xs[ci*Lin + li] * w[(size_t)ci*Co*3 + co*3 + k];
    a += aa;
  }
  y[(size_t)b*Co*Lout + co*Lout + lo] = a;
}

// =====================================================================
extern "C" void kernel_launch(void* const* d_in, const int* in_sizes, int n_in,
                              void* d_out, int out_size, void* d_ws, size_t ws_size,
                              hipStream_t stream){
  const int*   tokens = (const int*)  d_in[0];
  const float* tab    = (const float*)d_in[1];
  const float* w_ce = (const float*)d_in[2];  const float* b_ce = (const float*)d_in[3];
  const float* w_ct = (const float*)d_in[4];  const float* b_ct = (const float*)d_in[5];
  const float* w_cg = (const float*)d_in[6];  const float* b_cg = (const float*)d_in[7];
  const float* w_ces= (const float*)d_in[8];  const float* b_ces= (const float*)d_in[9];
  const float* w_cts= (const float*)d_in[10]; const float* b_cts= (const float*)d_in[11];
  const float* wi   = (const float*)d_in[12]; const float* bi   = (const float*)d_in[13];
  const float* wo   = (const float*)d_in[14]; const float* bo   = (const float*)d_in[15];
  const float* tgt1 = (const float*)d_in[16]; const float* tgt2 = (const float*)d_in[17];
  const float* w_mu = (const float*)d_in[18]; const float* b_mu = (const float*)d_in[19];
  const float* w_lv = (const float*)d_in[20]; const float* b_lv = (const float*)d_in[21];
  const float* w_di = (const float*)d_in[22]; const float* b_di = (const float*)d_in[23];
  const float* epsb = (const float*)d_in[24];
  const float* dk_w = (const float*)d_in[25]; const float* dk_b = (const float*)d_in[26];
  const float* dv_w = (const float*)d_in[27]; const float* dv_b = (const float*)d_in[28];
  const float* wt1  = (const float*)d_in[29]; const float* bt1  = (const float*)d_in[30];
  const float* wt2  = (const float*)d_in[31]; const float* bt2  = (const float*)d_in[32];
  const float* sq_w = (const float*)d_in[33]; const float* sq_b = (const float*)d_in[34];
  const float* sk_w = (const float*)d_in[35]; const float* sk_b = (const float*)d_in[36];
  const float* sv_w = (const float*)d_in[37]; const float* sv_b = (const float*)d_in[38];
  const float* wt3  = (const float*)d_in[39]; const float* bt3  = (const float*)d_in[40];

  float* dout = (float*)d_out;

  // ---- workspace carve ----
  char* ws = (char*)d_ws;
  size_t off = 0;
  auto take = [&](size_t bytes)->char*{ char* p = ws + off; off += (bytes + 255) & ~(size_t)255; return p; };
  bf16* EMB  = (bf16*)take(16777216ull*2);  // embeddings -> branch-e attn out
  bf16* HB   = (bf16*)take(16515072ull*2);  // conv_e out -> product P
  bf16* OB   = (bf16*)take(16515072ull*2);  // conv_t out -> conv_g out
  bf16* AE   = (bf16*)take(16515072ull*2);  // a_e
  bf16* TB   = (bf16*)take(16515072ull*2);  // branch-t attn out
  bf16* O1   = (bf16*)take(131072ull*2);
  bf16* OUTB = (bf16*)take(131072ull*2);
  bf16* SEB  = (bf16*)take(131072ull*2);
  bf16* SH   = (bf16*)take(126976ull*2);
  bf16* SCT  = (bf16*)take(126976ull*2);
  bf16* SO   = (bf16*)take(126976ull*2);
  bf16* SO2  = (bf16*)take(126976ull*2);
  bf16* SAE  = (bf16*)take(126976ull*2);
  bf16* XS   = (bf16*)take(126976ull*2);
  bf16* DO1  = (bf16*)take(2048ull*2);
  bf16* DOC  = (bf16*)take(2048ull*2);
  float* RK  = (float*)take(1024*4);
  float* PART= (float*)take(2016ull*2*4);
  float* STATS=(float*)take(32*4);
  float* DEC2= (float*)take(7168*4);
  float* C2  = (float*)take(26624*4);
  float* DEC3= (float*)take(26624*4);
  float* QC  = (float*)take(26624*4);
  float* KC  = (float*)take(26624*4);
  float* VC  = (float*)take(26624*4);
  float* DEC4= (float*)take(26624*4);
  float* C3  = (float*)take(26624*4);
  float* PET = (float*)take(16384*4);
  bf16* P_CE = (bf16*)take(49152ull*2);
  bf16* P_CT = (bf16*)take(49152ull*2);
  bf16* P_CG = (bf16*)take(49152ull*2);
  bf16* P_CES= (bf16*)take(49152ull*2);
  bf16* P_CTS= (bf16*)take(49152ull*2);
  bf16* P_WI = (bf16*)take(49152ull*2);
  bf16* P_WO = (bf16*)take(16384ull*2);
  (void)ws_size; (void)in_sizes; (void)n_in; (void)out_size;

  auto cdiv = [](long a, long b){ return (int)((a + b - 1)/b); };
  auto gemm = [&](const bf16* A, const bf16* Bpp, const float* bias, bf16* C, const bf16* mul,
                  int M, int N, int K, int a_lout, int a_lind, int lda, int NT, int n0t, int ldc, int act,
                  const float* lnst, int lngrp){
    dim3 g(cdiv(M,128), N/128, 1);
    if (lnst)
      k_gemm_mfma<false><<<g, 256, 0, stream>>>(A, Bpp, Bpp, bias, bias, C, C, mul,
                                                M, K, a_lout, a_lind, lda, NT, n0t, ldc, act, act, lnst, lngrp);
    else
      k_gemm_mfma<true><<<g, 256, 0, stream>>>(A, Bpp, Bpp, bias, bias, C, C, mul,
                                               M, K, a_lout, a_lind, lda, NT, n0t, ldc, act, act, nullptr, 0);
  };
  auto gemmz = [&](const bf16* A, const bf16* Bp1, const float* b1, bf16* C1, int act1,
                   const bf16* Bp2, const float* b2, bf16* C2p, int act2,
                   int M, int N, int K, int a_lout, int a_lind, int lda, int NT, int n0t, int ldc){
    dim3 g(cdiv(M,128), N/128, 2);
    k_gemm_mfma<true><<<g, 256, 0, stream>>>(A, Bp1, Bp2, b1, b2, C1, C2p, nullptr,
                                             M, K, a_lout, a_lind, lda, NT, n0t, ldc, act1, act2, nullptr, 0);
  };

  // ===== merged prep: embed (8192) + packs/PE (1280) + qprep (1) =====
  k_prep<<<9473, 256, 0, stream>>>(tokens, tab, w_ce, w_ct, w_cg, w_ces, w_cts, wi, wo,
                                   bi, tgt1, tgt2,
                                   P_CE, P_CT, P_CG, P_CES, P_CTS, P_WI, P_WO, PET, EMB, RK);

  // ===== word level =====
  // batched conv pair: z0 CE->HB(elu), z1 CT->OB(tanh)
  gemmz(EMB, P_CE, b_ce, HB, 1, P_CT, b_ct, OB, 2, 129024, 128, 384, 126, 16384, 0, 8, 0, 128);

  // merged word attention: blocks [0,4096) HB->EMB (branch e); [4096,8192) OB->TB (branch t)
  k_attn_fused<126><<<8192, 256, 0, stream>>>(HB, OB, P_WI, bi, EMB, TB, 4096);
  // wo(elu): EMB -> AE
  gemm(EMB, P_WO, bo, AE, nullptr, 129024, 128, 128, 0, 0, 128, 8, 0, 128, 1, nullptr, 0);
  // wo(tanh)*AE: TB -> HB (product)
  gemm(TB, P_WO, bo, HB, AE, 129024, 128, 128, 0, 0, 128, 8, 0, 128, 2, nullptr, 0);

  // big LN stats over HB; apply fused into conv_g A-load
  k_ln_partial<<<2016, 256, 0, stream>>>(HB, PART, 1032192, 126);
  k_ln_fin<<<16, 256, 0, stream>>>(PART, STATS, 126, 1032192);

  // conv g (elu) with fused LN: HB -> OB [1024,124,128]
  gemm(HB, P_CG, b_cg, OB, nullptr, 126976, 128, 384, 124, 16128, 0, 8, 0, 128, 1, STATS, 1032192);

  // fused target-query attention
  k_attn_tgt<124><<<1024, 256, 0, stream>>>(OB, RK, wi, bi, O1);
  gemm(O1, P_WO, bo, OUTB, nullptr, 1024, 128, 128, 0, 0, 128, 8, 0, 128, 0, nullptr, 0);

  // ===== sentence level =====
  k_se<<<512, 256, 0, stream>>>(OUTB, PET, SEB);

  gemmz(SEB, P_CES, b_ces, SH, 1, P_CTS, b_cts, SCT, 2, 992, 128, 384, 62, 8192, 0, 8, 0, 128);

  // merged sentence attention: [0,64) SH->SO; [64,128) SCT->SO2
  k_attn_fused<62><<<128, 256, 0, stream>>>(SH, SCT, P_WI, bi, SO, SO2, 64);
  gemm(SO, P_WO, bo, SAE, nullptr, 992, 128, 128, 0, 0, 128, 8, 0, 128, 1, nullptr, 0);
  gemm(SO2, P_WO, bo, SH, SAE, 992, 128, 128, 0, 0, 128, 8, 0, 128, 2, nullptr, 0);

  k_ln_small_bf16<<<16, 256, 0, stream>>>(SH, XS, 7936);

  k_attn_tgt<62><<<16, 256, 0, stream>>>(XS, RK + 512, wi, bi, DO1);
  gemm(DO1, P_WO, bo, DOC, nullptr, 16, 128, 128, 0, 0, 128, 8, 0, 128, 0, nullptr, 0);

  // ===== decoder (hybrid) =====
  k_dec_a<<<16, 256, 0, stream>>>(DOC, w_mu, b_mu, w_lv, b_lv, epsb, w_di, b_di,
                                  dk_w, dk_b, dv_w, dv_b, wt1, bt1, dout, DEC2);
  k_convt<<<16*8, 256, 0, stream>>>(DEC2, wt2, bt2, C2, 16, 64, 128, 7, 13, 2, 1, 8);
  k_ln_small_f32<<<16, 256, 0, stream>>>(C2, DEC3, 1664, 1);
  k_chanproj3<<<cdiv(26624,256), 256, 0, stream>>>(DEC3, sq_w, sq_b, sk_w, sk_b, sv_w, sv_b,
                                                   QC, KC, VC, 16, 128, 13);
  k_dec_attn2<<<64, 256, 0, stream>>>(QC, KC, VC, DEC4);
  k_convt<<<16*8, 256, 0, stream>>>(DEC4, wt3, bt3, C3, 16, 128, 128, 13, 13, 1, 1, 8);
  k_ln_small_f32<<<16, 256, 0, stream>>>(C3, dout, 1664, 3);
}

// Round 18
// 617.568 us; speedup vs baseline: 1.0271x; 1.0271x over previous
//
#include <hip/hip_runtime.h>
#include <hip/hip_bf16.h>

typedef __hip_bfloat16 bf16;
typedef __attribute__((ext_vector_type(8))) short bf16x8;
typedef __attribute__((ext_vector_type(4))) float f32x4;

__device__ __forceinline__ float b2f(bf16 x){ return __bfloat162float(x); }
__device__ __forceinline__ bf16  f2b(float x){ return __float2bfloat16(x); }
__device__ __forceinline__ unsigned short b2u(bf16 x){ union{bf16 b; unsigned short u;} c; c.b = x; return c.u; }

#define LOG2E 1.4426950408889634f
#define QSC (0.17677669529663687f * LOG2E)

#define GLD16(gp, lp) __builtin_amdgcn_global_load_lds( \
    (const __attribute__((address_space(1))) void*)(gp), \
    (__attribute__((address_space(3))) void*)(lp), 16, 0, 0)

__device__ __forceinline__ float fexp2(float x){       // v_exp_f32 = 2^x, ~1 ulp
  float r; asm("v_exp_f32 %0, %1" : "=v"(r) : "v"(x)); return r;
}
__device__ __forceinline__ float fast_exp(float x){ return fexp2(x * LOG2E); }
__device__ __forceinline__ float eluf(float x){ return x > 0.f ? x : fast_exp(x) - 1.f; }
__device__ __forceinline__ float fast_tanh(float x){
  float cx = fminf(fmaxf(x, -15.f), 15.f);
  float t = fexp2(cx * (2.f*LOG2E));
  return (t - 1.f) / (t + 1.f);
}

#define PE_C (-0.07195578415606394f)  /* -ln(10000)/128 */

__device__ __forceinline__ float pe_val(int pos, int d){
  int j2 = d & ~1;
  float ang = (float)pos * expf((float)j2 * PE_C);
  return (d & 1) ? cosf(ang) : sinf(ang);
}

// ---------------- merged prep: 7 weight packs + PE table ----------------
__device__ __forceinline__ void pack_one(const float* __restrict__ W, bf16* __restrict__ out,
                                         int K, int N, int conv, int qscale, int t){
  int j = t & 7, lane = (t >> 3) & 63;
  int rest = t >> 9; int NT = N >> 4;
  int nt = rest % NT; int kb = rest / NT;
  int k = kb*32 + ((lane >> 4) << 3) + j;
  int n = nt*16 + (lane & 15);
  float v = conv ? W[n*384 + (k & 127)*3 + (k >> 7)] : W[(long)n*K + k];
  if (qscale && n < 128) v *= QSC;
  out[t] = f2b(v);
}

__global__ void k_prep(const float* __restrict__ w_ce, const float* __restrict__ w_ct,
                       const float* __restrict__ w_cg, const float* __restrict__ w_ces,
                       const float* __restrict__ w_cts, const float* __restrict__ wi,
                       const float* __restrict__ wo,
                       bf16* P_CE, bf16* P_CT, bf16* P_CG, bf16* P_CES, bf16* P_CTS,
                       bf16* P_WI, bf16* P_WO, float* __restrict__ pet){
  int bid = blockIdx.x;
  if (bid < 1152){
    int grp = bid / 192; int t = (bid % 192)*256 + threadIdx.x;
    const float* W; bf16* out; int K, N, conv, qs = 0;
    if      (grp == 0){ W = w_ce;  out = P_CE;  K=384; N=128; conv=1; }
    else if (grp == 1){ W = w_ct;  out = P_CT;  K=384; N=128; conv=1; }
    else if (grp == 2){ W = w_cg;  out = P_CG;  K=384; N=128; conv=1; }
    else if (grp == 3){ W = w_ces; out = P_CES; K=384; N=128; conv=1; }
    else if (grp == 4){ W = w_cts; out = P_CTS; K=384; N=128; conv=1; }
    else              { W = wi;    out = P_WI;  K=128; N=384; conv=0; qs=1; }
    pack_one(W, out, K, N, conv, qs, t);
  } else if (bid < 1216){
    int t = (bid - 1152)*256 + threadIdx.x;
    pack_one(wo, P_WO, 128, 128, 0, 0, t);
  } else {
    int i = (bid - 1216)*256 + threadIdx.x;
    if (i < 16384) pet[i] = pe_val(i >> 7, i & 127);
  }
}

// ---------------- q-prep ----------------
__global__ void k_qprep(const float* __restrict__ wi, const float* __restrict__ bi,
                        const float* __restrict__ t1, const float* __restrict__ t2,
                        float* __restrict__ rkv){
  int tid = threadIdx.x;
  __shared__ float qps[256];
  {
    int which = tid >> 7, jj = tid & 127;
    const float* t = which ? t2 : t1;
    float a = bi[jj];
    for (int i = 0; i < 128; ++i) a += wi[jj*128 + i] * t[i];
    qps[tid] = a;
  }
  __syncthreads();
  int i = tid & 127, which = tid >> 7;
  for (int h = 0; h < 4; ++h){
    float a = 0.f;
    for (int d = 0; d < 32; ++d) a += qps[which*128 + h*32 + d] * wi[(128 + h*32 + d)*128 + i];
    rkv[which*512 + h*128 + i] = a;
  }
}

// ---------------- embedding + positional encoding ----------------
__global__ void k_embed8(const int* __restrict__ tok, const float* __restrict__ tab,
                         const float* __restrict__ pet, bf16* __restrict__ out){
  int t = blockIdx.x*256 + threadIdx.x;        // < 2097152
  int q = t & 15;
  int flat = t >> 4; int w = flat & 127;
  int tk = tok[flat];
  const float* ta = tab + tk*128 + q*8;
  const float* pe = pet + (w << 7) + q*8;
  bf16 ob[8];
  #pragma unroll
  for (int i = 0; i < 8; ++i) ob[i] = f2b(ta[i] + pe[i]);
  *(f32x4*)(out + (size_t)t*8) = *(f32x4*)ob;
}

__global__ void k_se(const bf16* __restrict__ in, const float* __restrict__ pet, bf16* __restrict__ out){
  int idx = blockIdx.x*256 + threadIdx.x;      // < 131072
  int d = idx & 127; int n = (idx >> 7) & 63;
  out[idx] = f2b(b2f(in[idx]) + pet[(n << 7) + d]);
}

// ---------------- MFMA GEMM, double-buffered 1-barrier pipeline ----------------
// GLL=true: async global_load_lds staging (linear LDS dest, inverse-swizzled per-lane source).
// GLL=false: reg-staged path (supports fused LayerNorm on A load).
template<bool GLL>
__global__ __launch_bounds__(256)
void k_gemm_mfma(const bf16* __restrict__ A, const bf16* __restrict__ Bp_, const bf16* __restrict__ Bp2,
                 const float* __restrict__ bias_, const float* __restrict__ bias2,
                 bf16* __restrict__ C_, bf16* __restrict__ C2p,
                 const bf16* __restrict__ mul,
                 int M, int K, int a_lout, int a_lind, int lda,
                 int NT, int n0t, int ldc, int act_, int act2,
                 const float* __restrict__ lnst, int lngrp){
  const bf16* Bp = Bp_; const float* bias = bias_; bf16* C = C_; int act = act_;
  if (blockIdx.z){ Bp = Bp2; bias = bias2; C = C2p; act = act2; }

  __shared__ f32x4 AsV[2][512];                 // 2 x 8 KB
  char* As0 = (char*)AsV[0];
  char* As1 = (char*)AsV[1];
  int tid = threadIdx.x;
  int lane = tid & 63, wave = tid >> 6;
  int wm = wave >> 1, wn = wave & 1;
  int m0 = blockIdx.x*128;
  int by = blockIdx.y;

  long offA[2]; bool okA[2]; float lnm[2], lnr[2]; int sbyte[2];
  #pragma unroll
  for (int p = 0; p < 2; ++p){
    int e = tid + p*256;
    int row, kq;
    if (GLL){
      // inverse of slot swizzle: slot x holds (row,kq) with x = (row<<2|kq) ^ (row&7)
      int x = e;
      row = (((x >> 3) << 1) | (((x >> 2) ^ (x >> 4)) & 1)) & 127;
      kq  = ((((x >> 1) ^ (x >> 3)) & 1) << 1) | ((x ^ (x >> 2) ^ (x >> 4)) & 1);
    } else {
      row = e >> 2; kq = e & 3;
    }
    int m = m0 + row;
    okA[p] = (m < M);
    long off = 0;
    if (okA[p]){
      off = (a_lout > 0) ? (long)(m / a_lout)*a_lind + (long)(m % a_lout)*128 + kq*8
                         : (long)m*lda + kq*8;
    }
    offA[p] = off;
    lnm[p] = 0.f; lnr[p] = 1.f;
    if (!GLL && lnst && okA[p]){ int g = (int)(off / (long)lngrp); lnm[p] = lnst[2*g]; lnr[p] = lnst[2*g+1]; }
    sbyte[p] = (row*64 + kq*16) ^ ((row & 7) << 4);
  }

  const bf16* bptr[4];
  size_t bstep = (size_t)NT*512;
  #pragma unroll
  for (int fn = 0; fn < 4; ++fn){
    int ntile = n0t + by*8 + wn*4 + fn;
    bptr[fn] = Bp + ((size_t)ntile*64 + lane)*8;
  }
  int abyte[4];
  #pragma unroll
  for (int fm = 0; fm < 4; ++fm){
    int row = wm*64 + fm*16 + (lane & 15);
    abyte[fm] = (row*64 + ((lane >> 4) << 4)) ^ ((row & 7) << 4);
  }

  f32x4 acc[4][4];
  #pragma unroll
  for (int i = 0; i < 4; ++i)
    #pragma unroll
    for (int j = 0; j < 4; ++j) acc[i][j] = (f32x4){0.f,0.f,0.f,0.f};

  int nk = K >> 5;

  if constexpr (GLL){
    int ldsw = (tid >> 6)*1024;
    #pragma unroll
    for (int p = 0; p < 2; ++p)
      GLD16(A + offA[p], As0 + p*4096 + ldsw);
    __syncthreads();
    for (int kb = 0; kb < nk; ++kb){
      char* cur = (kb & 1) ? As1 : As0;
      char* nxt = (kb & 1) ? As0 : As1;
      bool more = (kb + 1) < nk;
      if (more){
        #pragma unroll
        for (int p = 0; p < 2; ++p)
          GLD16(A + offA[p] + (kb+1)*32, nxt + p*4096 + ldsw);
      }
      bf16x8 bfr[4];
      #pragma unroll
      for (int fn = 0; fn < 4; ++fn) bfr[fn] = *(const bf16x8*)(bptr[fn] + (size_t)kb*bstep);
      bf16x8 afr[4];
      #pragma unroll
      for (int fm = 0; fm < 4; ++fm) afr[fm] = *(const bf16x8*)(cur + abyte[fm]);
      #pragma unroll
      for (int fm = 0; fm < 4; ++fm)
        #pragma unroll
        for (int fn = 0; fn < 4; ++fn)
          acc[fm][fn] = __builtin_amdgcn_mfma_f32_16x16x32_bf16(afr[fm], bfr[fn], acc[fm][fn], 0, 0, 0);
      __syncthreads();
    }
  } else {
    auto loadA = [&](int p, int kb)->float4{
      float4 v = make_float4(0.f,0.f,0.f,0.f);
      if (okA[p]){
        v = *(const float4*)(A + offA[p] + kb*32);
        if (lnst){
          bf16* pp = (bf16*)&v; bf16 oo[8];
          #pragma unroll
          for (int u = 0; u < 8; ++u) oo[u] = f2b((b2f(pp[u]) - lnm[p]) * lnr[p]);
          v = *(float4*)&oo[0];
        }
      }
      return v;
    };
    float4 va0 = loadA(0, 0), va1 = loadA(1, 0);
    *(float4*)(As0 + sbyte[0]) = va0;
    *(float4*)(As0 + sbyte[1]) = va1;
    __syncthreads();
    for (int kb = 0; kb < nk; ++kb){
      char* cur = (kb & 1) ? As1 : As0;
      char* nxt = (kb & 1) ? As0 : As1;
      bool more = (kb + 1) < nk;
      if (more){ va0 = loadA(0, kb+1); va1 = loadA(1, kb+1); }  // issue early
      bf16x8 bfr[4];
      #pragma unroll
      for (int fn = 0; fn < 4; ++fn) bfr[fn] = *(const bf16x8*)(bptr[fn] + (size_t)kb*bstep);
      bf16x8 afr[4];
      #pragma unroll
      for (int fm = 0; fm < 4; ++fm) afr[fm] = *(const bf16x8*)(cur + abyte[fm]);
      #pragma unroll
      for (int fm = 0; fm < 4; ++fm)
        #pragma unroll
        for (int fn = 0; fn < 4; ++fn)
          acc[fm][fn] = __builtin_amdgcn_mfma_f32_16x16x32_bf16(afr[fm], bfr[fn], acc[fm][fn], 0, 0, 0);
      if (more){
        *(float4*)(nxt + sbyte[0]) = va0;   // write late
        *(float4*)(nxt + sbyte[1]) = va1;
      }
      __syncthreads();
    }
  }

  #pragma unroll
  for (int fm = 0; fm < 4; ++fm){
    #pragma unroll
    for (int r = 0; r < 4; ++r){
      int m = m0 + wm*64 + fm*16 + ((lane >> 4) << 2) + r;
      if (m >= M) continue;
      #pragma unroll
      for (int fn = 0; fn < 4; ++fn){
        int n = by*128 + wn*64 + fn*16 + (lane & 15);
        float v = acc[fm][fn][r] + (bias ? bias[n] : 0.f);
        if (act == 1) v = eluf(v);
        else if (act == 2) v = fast_tanh(v);
        if (mul) v *= b2f(mul[(long)m*ldc + n]);
        C[(long)m*ldc + n] = f2b(v);
      }
    }
  }
}

// ---------------- fused QKV-projection + MFMA self-attention ----------------
// Two independent branches merged into one dispatch: blocks >= nhalf use (X2, o2).
template<int L>
__global__ __launch_bounds__(256)
void k_attn_fused(const bf16* __restrict__ X, const bf16* __restrict__ X2,
                  const bf16* __restrict__ Pwi, const float* __restrict__ bi,
                  bf16* __restrict__ o, bf16* __restrict__ o2, int nhalf){
  constexpr int KB  = (L + 31) / 32;   // PV K-steps
  constexpr int MT  = KB * 2;          // 16-row tiles
  constexpr int WMT = MT / 4;          // M-tiles per wave
  constexpr int NP  = KB * 32;         // padded seq len
  constexpr int PRS = NP * 2;          // P row stride bytes

  __shared__ alignas(16) char As[NP*256];   // X tile; aliased by Pb
  __shared__ alignas(16) char Qb[NP*64];
  __shared__ alignas(16) char Kb[NP*64];
  __shared__ alignas(16) char Vt[32*PRS];
  char* Pb = As;

  int tid = threadIdx.x;
  int bid = blockIdx.x;
  const bf16* Xp = X; bf16* op = o;
  if (bid >= nhalf){ Xp = X2; op = o2; bid -= nhalf; }
  int s = bid >> 2, h = bid & 3;
  const bf16* xb = Xp + (size_t)s*L*128;

  {
    constexpr int NCH = (NP*16)/256;
    int ldsw = (tid >> 6)*1024;
    #pragma unroll
    for (int p = 0; p < NCH; ++p){
      int x = p*256 + tid;
      int row = x >> 4;
      int c = (x & 15) ^ (row & 7);
      const bf16* gp = (row < L) ? (xb + (size_t)row*128 + c*8) : xb;
      GLD16(gp, As + p*4096 + ldsw);
    }
  }
  __syncthreads();

  int lane = tid & 63, wave = tid >> 6;
  int col = lane & 15;

  // ---- projection ----
  __builtin_amdgcn_s_setprio(1);
  #pragma unroll
  for (int mt = 0; mt < WMT; ++mt){
    int mtile = wave*WMT + mt;
    int arow = mtile*16 + col;
    bf16x8 a4[4];
    #pragma unroll
    for (int kb = 0; kb < 4; ++kb)
      a4[kb] = *(const bf16x8*)(As + ((arow*256 + kb*64 + ((lane >> 4) << 4)) ^ ((arow & 7) << 4)));
    #pragma unroll
    for (int which = 0; which < 3; ++which){
      f32x4 av[2];
      #pragma unroll
      for (int nt = 0; nt < 2; ++nt){
        int ntile = which*8 + h*2 + nt;
        float bia = bi[which*128 + h*32 + nt*16 + col];
        if (which == 0) bia *= QSC;
        av[nt] = (f32x4){bia, bia, bia, bia};
        #pragma unroll
        for (int kb = 0; kb < 4; ++kb){
          bf16x8 bfr = *(const bf16x8*)(Pwi + (((size_t)kb*24 + ntile)*64 + lane)*8);
          av[nt] = __builtin_amdgcn_mfma_f32_16x16x32_bf16(a4[kb], bfr, av[nt], 0, 0, 0);
        }
      }
      #pragma unroll
      for (int r = 0; r < 4; ++r){
        int row = mtile*16 + ((lane >> 4) << 2) + r;
        if (which < 2){
          unsigned pk = (unsigned)b2u(f2b(av[0][r])) | ((unsigned)b2u(f2b(av[1][r])) << 16);
          char* dst = which ? Kb : Qb;
          *(unsigned*)(dst + ((row*64 + col*4) ^ ((row & 7) << 4))) = pk;
        } else {
          int pos = (row & 15)*MT + (row >> 4);
          #pragma unroll
          for (int nt = 0; nt < 2; ++nt){
            int d = nt*16 + col;
            *(bf16*)(Vt + ((d*PRS + pos*2) ^ ((d & 7) << 4))) = f2b(av[nt][r]);
          }
        }
      }
    }
  }
  __builtin_amdgcn_s_setprio(0);
  __syncthreads();

  // ---- QK^T (scores in log2 units) ----
  f32x4 acc[WMT][MT];
  #pragma unroll
  for (int mt = 0; mt < WMT; ++mt)
    #pragma unroll
    for (int nt = 0; nt < MT; ++nt) acc[mt][nt] = (f32x4){0.f,0.f,0.f,0.f};

  bf16x8 af[WMT];
  #pragma unroll
  for (int mt = 0; mt < WMT; ++mt){
    int row = (wave*WMT + mt)*16 + col;
    af[mt] = *(const bf16x8*)(Qb + ((row*64 + ((lane >> 4) << 4)) ^ ((row & 7) << 4)));
  }
  __builtin_amdgcn_s_setprio(1);
  #pragma unroll
  for (int nt = 0; nt < MT; ++nt){
    int rk2 = nt*16 + col;
    bf16x8 bfk = *(const bf16x8*)(Kb + ((rk2*64 + ((lane >> 4) << 4)) ^ ((rk2 & 7) << 4)));
    #pragma unroll
    for (int mt = 0; mt < WMT; ++mt)
      acc[mt][nt] = __builtin_amdgcn_mfma_f32_16x16x32_bf16(af[mt], bfk, acc[mt][nt], 0, 0, 0);
  }
  __builtin_amdgcn_s_setprio(0);

  // ---- softmax: mask last col-tile, single v_exp, packed P write, deferred normalize ----
  const bool lastMask = col >= (L - (MT-1)*16);
  float pinv[WMT][4];
  #pragma unroll
  for (int mt = 0; mt < WMT; ++mt){
    #pragma unroll
    for (int r = 0; r < 4; ++r){
      float mx = -1e30f;
      #pragma unroll
      for (int nt = 0; nt < MT; ++nt){
        float v = acc[mt][nt][r];
        if (nt == MT-1 && lastMask){ v = -1e30f; acc[mt][nt][r] = v; }
        mx = fmaxf(mx, v);
      }
      mx = fmaxf(mx, __shfl_xor(mx, 1));
      mx = fmaxf(mx, __shfl_xor(mx, 2));
      mx = fmaxf(mx, __shfl_xor(mx, 4));
      mx = fmaxf(mx, __shfl_xor(mx, 8));
      float sum = 0.f;
      bf16 prow[MT];
      #pragma unroll
      for (int nt = 0; nt < MT; ++nt){
        float p = fexp2(acc[mt][nt][r] - mx);
        prow[nt] = f2b(p);
        sum += p;
      }
      sum += __shfl_xor(sum, 1);
      sum += __shfl_xor(sum, 2);
      sum += __shfl_xor(sum, 4);
      sum += __shfl_xor(sum, 8);
      pinv[mt][r] = 1.f / sum;
      int row = (wave*WMT + mt)*16 + ((lane >> 4) << 2) + r;
      char* dst = Pb + ((row*PRS + col*(MT*2)) ^ ((row & 7) << 4));
      if constexpr (MT == 8) *(f32x4*)dst = *(f32x4*)prow;
      else                   *(float2*)dst = *(float2*)prow;
    }
  }

  // ---- PV (same-wave rows; no barrier), normalize at output ----
  #pragma unroll
  for (int mt = 0; mt < WMT; ++mt){
    int mtile = wave*WMT + mt;
    f32x4 o0 = (f32x4){0.f,0.f,0.f,0.f}, o1 = (f32x4){0.f,0.f,0.f,0.f};
    __builtin_amdgcn_s_setprio(1);
    #pragma unroll
    for (int kb = 0; kb < KB; ++kb){
      int row = mtile*16 + col;
      bf16x8 pa = *(const bf16x8*)(Pb + ((row*PRS + kb*64 + ((lane >> 4) << 4)) ^ ((row & 7) << 4)));
      int d0 = col;
      bf16x8 v0 = *(const bf16x8*)(Vt + ((d0*PRS + kb*64 + ((lane >> 4) << 4)) ^ ((d0 & 7) << 4)));
      bf16x8 v1 = *(const bf16x8*)(Vt + (((d0+16)*PRS + kb*64 + ((lane >> 4) << 4)) ^ (((d0+16) & 7) << 4)));
      o0 = __builtin_amdgcn_mfma_f32_16x16x32_bf16(pa, v0, o0, 0, 0, 0);
      o1 = __builtin_amdgcn_mfma_f32_16x16x32_bf16(pa, v1, o1, 0, 0, 0);
    }
    __builtin_amdgcn_s_setprio(0);
    #pragma unroll
    for (int r = 0; r < 4; ++r){
      int row = mtile*16 + ((lane >> 4) << 2) + r;
      if (row < L){
        size_t ob = ((size_t)s*L + row)*128 + h*32 + col;
        op[ob]      = f2b(o0[r] * pinv[mt][r]);
        op[ob + 16] = f2b(o1[r] * pinv[mt][r]);
      }
    }
  }
}

// ---------------- fused target-query attention ----------------
template<int L>
__global__ __launch_bounds__(256)
void k_attn_tgt(const bf16* __restrict__ hin, const float* __restrict__ rk,
                const float* __restrict__ wi, const float* __restrict__ bi,
                bf16* __restrict__ outp){
  __shared__ alignas(16) char Hs[L*256];
  __shared__ float RKs[512];
  __shared__ float Ps[512];
  __shared__ float Cs[512];
  int tid = threadIdx.x, lane = tid & 63, wave = tid >> 6;
  int s = blockIdx.x;
  const bf16* hb = hin + (size_t)s*L*128;
  for (int e = tid; e < L*16; e += 256){
    int row = e >> 4, c = e & 15;
    *(float4*)(Hs + row*256 + ((c ^ (row & 7)) << 4)) = *(const float4*)(hb + row*128 + c*8);
  }
  for (int e = tid; e < 512; e += 256) RKs[e] = rk[e];
  __syncthreads();

  int j0 = lane, j1 = lane + 64;
  float v0 = -1e30f, v1 = -1e30f;
  if (j0 < L){
    float a = 0.f;
    #pragma unroll
    for (int c = 0; c < 16; ++c){
      bf16x8 x = *(const bf16x8*)(Hs + j0*256 + ((c ^ (j0 & 7)) << 4));
      #pragma unroll
      for (int u = 0; u < 8; ++u) a += b2f(((bf16*)&x)[u]) * RKs[wave*128 + c*8 + u];
    }
    v0 = a * 0.17677669529663687f;
  }
  if (j1 < L){
    float a = 0.f;
    #pragma unroll
    for (int c = 0; c < 16; ++c){
      bf16x8 x = *(const bf16x8*)(Hs + j1*256 + ((c ^ (j1 & 7)) << 4));
      #pragma unroll
      for (int u = 0; u < 8; ++u) a += b2f(((bf16*)&x)[u]) * RKs[wave*128 + c*8 + u];
    }
    v1 = a * 0.17677669529663687f;
  }
  float mx = fmaxf(v0, v1);
  #pragma unroll
  for (int off = 32; off; off >>= 1) mx = fmaxf(mx, __shfl_xor(mx, off));
  float e0 = (j0 < L) ? fast_exp(v0 - mx) : 0.f;
  float e1 = (j1 < L) ? fast_exp(v1 - mx) : 0.f;
  float sum = e0 + e1;
  #pragma unroll
  for (int off = 32; off; off >>= 1) sum += __shfl_xor(sum, off);
  float inv = 1.f / sum;
  Ps[wave*128 + j0] = e0 * inv;
  Ps[wave*128 + j1] = e1 * inv;

  int i0 = lane*2;
  float c0 = 0.f, c1 = 0.f;
  for (int j = 0; j < L; ++j){
    float p = Ps[wave*128 + j];
    short2 w2 = *(const short2*)(Hs + j*256 + (((i0 >> 3) ^ (j & 7)) << 4) + (i0 & 7)*2);
    c0 += p * b2f(*(bf16*)&w2.x);
    c1 += p * b2f(*(bf16*)&w2.y);
  }
  Cs[wave*128 + i0]     = c0;
  Cs[wave*128 + i0 + 1] = c1;
  __syncthreads();

  if (tid < 128){
    int h2 = tid >> 5;
    float a = bi[256 + tid];
    const float* wr = wi + (size_t)(256 + tid)*128;
    for (int i = 0; i < 128; ++i) a += wr[i] * Cs[h2*128 + i];
    outp[(size_t)s*128 + tid] = f2b(a);
  }
}

// ---------------- big LayerNorm stats: partial / finalize ----------------
__global__ void k_ln_partial(const bf16* __restrict__ x, float* __restrict__ part, int GS, int P){
  int pi = blockIdx.x % P;
  int chunk8 = GS / P / 8;
  size_t base = (size_t)(blockIdx.x / P)*GS + (size_t)pi*(GS/P);
  float s = 0.f, s2 = 0.f;
  for (int i = threadIdx.x; i < chunk8; i += 256){
    f32x4 raw = *(const f32x4*)(x + base + (size_t)i*8);
    const bf16* xb = (const bf16*)&raw;
    #pragma unroll
    for (int j = 0; j < 8; ++j){ float v = b2f(xb[j]); s += v; s2 += v*v; }
  }
  #pragma unroll
  for (int off = 32; off; off >>= 1){ s += __shfl_xor(s, off); s2 += __shfl_xor(s2, off); }
  __shared__ float sh[8];
  int lane = threadIdx.x & 63, wv = threadIdx.x >> 6;
  if (lane == 0){ sh[wv] = s; sh[4 + wv] = s2; }
  __syncthreads();
  if (threadIdx.x == 0){
    part[blockIdx.x*2]     = sh[0]+sh[1]+sh[2]+sh[3];
    part[blockIdx.x*2 + 1] = sh[4]+sh[5]+sh[6]+sh[7];
  }
}

__global__ void k_ln_fin(const float* __restrict__ part, float* __restrict__ stats, int P, int GS){
  int g = blockIdx.x;
  float s = 0.f, s2 = 0.f;
  for (int i = threadIdx.x; i < P; i += 256){ s += part[(g*P + i)*2]; s2 += part[(g*P + i)*2 + 1]; }
  #pragma unroll
  for (int off = 32; off; off >>= 1){ s += __shfl_xor(s, off); s2 += __shfl_xor(s2, off); }
  __shared__ float sh[8];
  int lane = threadIdx.x & 63, wv = threadIdx.x >> 6;
  if (lane == 0){ sh[wv] = s; sh[4 + wv] = s2; }
  __syncthreads();
  if (threadIdx.x == 0){
    float S = sh[0]+sh[1]+sh[2]+sh[3], S2 = sh[4]+sh[5]+sh[6]+sh[7];
    float mean = S / GS;
    float var = S2 / GS - mean*mean;
    stats[g*2] = mean; stats[g*2 + 1] = rsqrtf(var + 1e-5f);
  }
}

// ---------------- small LN (bf16), one block per group ----------------
__global__ void k_ln_small_bf16(const bf16* __restrict__ x, bf16* __restrict__ y, int n){
  int g = blockIdx.x;
  const bf16* xb = x + (size_t)g*n;
  bf16* yb = y + (size_t)g*n;
  float s = 0.f, s2 = 0.f;
  for (int i = threadIdx.x; i < n; i += 256){ float v = b2f(xb[i]); s += v; s2 += v*v; }
  #pragma unroll
  for (int off = 32; off; off >>= 1){ s += __shfl_xor(s, off); s2 += __shfl_xor(s2, off); }
  __shared__ float sh[8];  __shared__ float ms[2];
  int lane = threadIdx.x & 63, wv = threadIdx.x >> 6;
  if (lane == 0){ sh[wv] = s; sh[4 + wv] = s2; }
  __syncthreads();
  if (threadIdx.x == 0){
    float S = sh[0]+sh[1]+sh[2]+sh[3], S2 = sh[4]+sh[5]+sh[6]+sh[7];
    float mean = S / n;
    ms[0] = mean; ms[1] = rsqrtf(S2 / n - mean*mean + 1e-5f);
  }
  __syncthreads();
  float mean = ms[0], inv = ms[1];
  for (int i = threadIdx.x; i < n; i += 256) yb[i] = f2b((b2f(xb[i]) - mean)*inv);
}

// ---------------- small LN (f32), one block per group ----------------
__global__ void k_ln_small_f32(const float* __restrict__ x, float* __restrict__ y, int n, int act){
  int g = blockIdx.x;
  const float* xb = x + (size_t)g*n;
  float* yb = y + (size_t)g*n;
  float s = 0.f, s2 = 0.f;
  for (int i = threadIdx.x; i < n; i += 256){ float v = xb[i]; s += v; s2 += v*v; }
  #pragma unroll
  for (int off = 32; off; off >>= 1){ s += __shfl_xor(s, off); s2 += __shfl_xor(s2, off); }
  __shared__ float sh[8];  __shared__ float ms[2];
  int lane = threadIdx.x & 63, wv = threadIdx.x >> 6;
  if (lane == 0){ sh[wv] = s; sh[4 + wv] = s2; }
  __syncthreads();
  if (threadIdx.x == 0){
    float S = sh[0]+sh[1]+sh[2]+sh[3], S2 = sh[4]+sh[5]+sh[6]+sh[7];
    float mean = S / n;
    ms[0] = mean; ms[1] = rsqrtf(S2 / n - mean*mean + 1e-5f);
  }
  __syncthreads();
  float mean = ms[0], inv = ms[1];
  for (int i = threadIdx.x; i < n; i += 256){
    float v = (xb[i] - mean)*inv;
    if (act == 1) v = eluf(v);
    else if (act == 3) v = 1.f/(1.f + fast_exp(-v));
    yb[i] = v;
  }
}

// ---------------- decoder stage A (tiny front chain), one block per b ----------------
__global__ __launch_bounds__(256)
void k_dec_a(const bf16* __restrict__ DOC,
             const float* __restrict__ w_mu, const float* __restrict__ b_mu,
             const float* __restrict__ w_lv, const float* __restrict__ b_lv,
             const float* __restrict__ eps,
             const float* __restrict__ w_di, const float* __restrict__ b_di,
             const float* __restrict__ dk_w, const float* __restrict__ dk_b,
             const float* __restrict__ dv_w, const float* __restrict__ dv_b,
             const float* __restrict__ wt1, const float* __restrict__ bt1,
             float* __restrict__ dout, float* __restrict__ DEC2){
  int b = blockIdx.x, tid = threadIdx.x;
  __shared__ float Zs[128], H3[128], KD[128], VD[128], D1[128];
  __shared__ float C1[448];
  __shared__ float sc[64];
  __shared__ float red[8], ms[2];

  if (tid < 128){
    const bf16* dr = DOC + b*128;
    float mu = b_mu[tid], lv = b_lv[tid];
    for (int i = 0; i < 128; ++i){
      float x = b2f(dr[i]);
      mu += x * w_mu[tid*128 + i];
      lv += x * w_lv[tid*128 + i];
    }
    dout[26624 + b*128 + tid] = mu;
    dout[28672 + b*128 + tid] = lv;
    Zs[tid] = mu + eps[b*128 + tid] * fast_exp(0.5f*lv);
  }
  __syncthreads();
  if (tid < 128){
    float a = b_di[tid];
    for (int i = 0; i < 128; ++i) a += Zs[i] * w_di[tid*128 + i];
    H3[tid] = a;
  }
  __syncthreads();
  if (tid < 128){
    int l = tid & 3, o2 = tid >> 2;
    float ak = dk_b[o2], av = dv_b[o2];
    for (int i = 0; i < 32; ++i){
      float xv = H3[i*4 + l];
      ak += dk_w[o2*32 + i]*xv;
      av += dv_w[o2*32 + i]*xv;
    }
    KD[tid] = ak; VD[tid] = av;
  }
  __syncthreads();
  if (tid < 64){
    int h = tid >> 4, l = (tid >> 2) & 3, m = tid & 3;
    float a = 0.f;
    #pragma unroll
    for (int d = 0; d < 8; ++d) a += KD[(h*8+d)*4 + l] * VD[(h*8+d)*4 + m];
    sc[tid] = a * 0.35355339059327373f;
  }
  __syncthreads();
  if (tid < 16){
    int base = tid*4;
    float mx = fmaxf(fmaxf(sc[base],sc[base+1]),fmaxf(sc[base+2],sc[base+3]));
    float e0=fast_exp(sc[base]-mx), e1=fast_exp(sc[base+1]-mx), e2=fast_exp(sc[base+2]-mx), e3=fast_exp(sc[base+3]-mx);
    float inv = 1.f/(e0+e1+e2+e3);
    sc[base]=e0*inv; sc[base+1]=e1*inv; sc[base+2]=e2*inv; sc[base+3]=e3*inv;
  }
  __syncthreads();
  if (tid < 128){
    int h = tid >> 5, rem = tid & 31, l = rem >> 3, d = rem & 7;
    float a = 0.f;
    #pragma unroll
    for (int m = 0; m < 4; ++m) a += sc[h*16 + l*4 + m] * VD[(h*8+d)*4 + m];
    D1[tid] = eluf(a);
  }
  __syncthreads();
  for (int idx = tid; idx < 448; idx += 256){
    int co = idx / 7, lo = idx % 7;
    float a = bt1[co];
    for (int k = 0; k < 3; ++k){
      int t = lo + 1 - k;
      if (t < 0 || (t & 1)) continue;
      int li = t >> 1; if (li >= 4) continue;
      float aa = 0.f;
      for (int ci = 0; ci < 32; ++ci) aa += D1[ci*4 + li] * wt1[ci*192 + co*3 + k];
      a += aa;
    }
    C1[idx] = a;
  }
  __syncthreads();
  {
    float s = 0.f, s2 = 0.f;
    for (int i = tid; i < 448; i += 256){ float v = C1[i]; s += v; s2 += v*v; }
    #pragma unroll
    for (int o = 32; o; o >>= 1){ s += __shfl_xor(s, o); s2 += __shfl_xor(s2, o); }
    int lane = tid & 63, wv = tid >> 6;
    if (lane == 0){ red[wv] = s; red[4+wv] = s2; }
    __syncthreads();
    if (tid == 0){
      float S = red[0]+red[1]+red[2]+red[3], S2 = red[4]+red[5]+red[6]+red[7];
      float mean = S/448.f; ms[0] = mean; ms[1] = rsqrtf(S2/448.f - mean*mean + 1e-5f);
    }
    __syncthreads();
    float mean = ms[0], inv = ms[1];
    for (int i = tid; i < 448; i += 256)
      DEC2[b*448 + i] = eluf((C1[i]-mean)*inv);
  }
}

// three channel-projections sharing one input read
__global__ void k_chanproj3(const float* __restrict__ x,
                            const float* __restrict__ w1, const float* __restrict__ b1,
                            const float* __restrict__ w2, const float* __restrict__ b2,
                            const float* __restrict__ w3, const float* __restrict__ b3,
                            float* __restrict__ y1, float* __restrict__ y2, float* __restrict__ y3,
                            int Bn, int C, int L){
  int idx = blockIdx.x*256 + threadIdx.x;
  if (idx >= Bn*C*L) return;
  int l = idx % L; int t2 = idx / L; int o = t2 % C; int b = t2 / C;
  float a1 = b1[o], a2 = b2[o], a3 = b3[o];
  const float* xb = x + (size_t)b*C*L + l;
  for (int i = 0; i < C; ++i){
    float xv = xb[i*L];
    a1 += w1[(size_t)o*C + i]*xv;
    a2 += w2[(size_t)o*C + i]*xv;
    a3 += w3[(size_t)o*C + i]*xv;
  }
  y1[idx] = a1; y2[idx] = a2; y3[idx] = a3;
}

__global__ __launch_bounds__(256)
void k_dec_attn2(const float* __restrict__ qc, const float* __restrict__ kc,
                 const float* __restrict__ vc, float* __restrict__ out){
  int b = blockIdx.x >> 2, h = blockIdx.x & 3, tid = threadIdx.x;
  __shared__ float sc[169];
  const float* qb = qc + b*1664 + h*416;
  const float* kb = kc + b*1664 + h*416;
  const float* vb = vc + b*1664 + h*416;
  if (tid < 169){
    int l = tid/13, m = tid - l*13;
    float a = 0.f;
    #pragma unroll
    for (int d = 0; d < 32; ++d) a += qb[d*13 + l] * kb[d*13 + m];
    sc[tid] = a * 0.17677669529663687f;
  }
  __syncthreads();
  if (tid < 13){
    float mx = -1e30f;
    for (int m = 0; m < 13; ++m) mx = fmaxf(mx, sc[tid*13 + m]);
    float s = 0.f;
    for (int m = 0; m < 13; ++m){ float p = fast_exp(sc[tid*13 + m] - mx); sc[tid*13 + m] = p; s += p; }
    float inv = 1.f/s;
    for (int m = 0; m < 13; ++m) sc[tid*13 + m] *= inv;
  }
  __syncthreads();
  for (int idx = tid; idx < 416; idx += 256){
    int l = idx >> 5, d = idx & 31;
    float a = 0.f;
    for (int m = 0; m < 13; ++m) a += sc[l*13 + m] * vb[m*32 + d];
    out[b*1664 + h*416 + idx] = eluf(a);
  }
}

// ConvTranspose1d (K=3), x staged in LDS
__global__ __launch_bounds__(256)
void k_convt(const float* __restrict__ x, const float* __restrict__ w,
             const float* __restrict__ bias, float* __restrict__ y,
             int Bn, int Ci, int Co, int Lin, int Lout, int stride, int pad, int nch){
  __shared__ float xs[1664];
  int b = blockIdx.x / nch;
  int c0 = (blockIdx.x % nch)*16;
  int tid = threadIdx.x;
  for (int i = tid; i < Ci*Lin; i += 256) xs[i] = x[(size_t)b*Ci*Lin + i];
  __syncthreads();
  int co = c0 + (tid & 15);
  int lo = tid >> 4;
  if (co >= Co || lo >= Lout) return;
  float a = bias[co];
  for (int k = 0; k < 3; ++k){
    int t = lo + pad - k;
    if (t < 0 || (t % stride)) continue;
    int li = t / stride;
    if (li >= Lin) continue;
    float aa = 0.f;
    for (int ci = 0; ci < Ci; ++ci) aa += xs[ci*Lin + li] * w[(size_t)ci*Co*3 + co*3 + k];
    a += aa;
  }
  y[(size_t)b*Co*Lout + co*Lout + lo] = a;
}

// =====================================================================
extern "C" void kernel_launch(void* const* d_in, const int* in_sizes, int n_in,
                              void* d_out, int out_size, void* d_ws, size_t ws_size,
                              hipStream_t stream){
  const int*   tokens = (const int*)  d_in[0];
  const float* tab    = (const float*)d_in[1];
  const float* w_ce = (const float*)d_in[2];  const float* b_ce = (const float*)d_in[3];
  const float* w_ct = (const float*)d_in[4];  const float* b_ct = (const float*)d_in[5];
  const float* w_cg = (const float*)d_in[6];  const float* b_cg = (const float*)d_in[7];
  const float* w_ces= (const float*)d_in[8];  const float* b_ces= (const float*)d_in[9];
  const float* w_cts= (const float*)d_in[10]; const float* b_cts= (const float*)d_in[11];
  const float* wi   = (const float*)d_in[12]; const float* bi   = (const float*)d_in[13];
  const float* wo   = (const float*)d_in[14]; const float* bo   = (const float*)d_in[15];
  const float* tgt1 = (const float*)d_in[16]; const float* tgt2 = (const float*)d_in[17];
  const float* w_mu = (const float*)d_in[18]; const float* b_mu = (const float*)d_in[19];
  const float* w_lv = (const float*)d_in[20]; const float* b_lv = (const float*)d_in[21];
  const float* w_di = (const float*)d_in[22]; const float* b_di = (const float*)d_in[23];
  const float* epsb = (const float*)d_in[24];
  const float* dk_w = (const float*)d_in[25]; const float* dk_b = (const float*)d_in[26];
  const float* dv_w = (const float*)d_in[27]; const float* dv_b = (const float*)d_in[28];
  const float* wt1  = (const float*)d_in[29]; const float* bt1  = (const float*)d_in[30];
  const float* wt2  = (const float*)d_in[31]; const float* bt2  = (const float*)d_in[32];
  const float* sq_w = (const float*)d_in[33]; const float* sq_b = (const float*)d_in[34];
  const float* sk_w = (const float*)d_in[35]; const float* sk_b = (const float*)d_in[36];
  const float* sv_w = (const float*)d_in[37]; const float* sv_b = (const float*)d_in[38];
  const float* wt3  = (const float*)d_in[39]; const float* bt3  = (const float*)d_in[40];

  float* dout = (float*)d_out;

  // ---- workspace carve ----
  char* ws = (char*)d_ws;
  size_t off = 0;
  auto take = [&](size_t bytes)->char*{ char* p = ws + off; off += (bytes + 255) & ~(size_t)255; return p; };
  bf16* EMB  = (bf16*)take(16777216ull*2);  // embeddings -> branch-e attn out
  bf16* HB   = (bf16*)take(16515072ull*2);  // conv_e out -> product P
  bf16* OB   = (bf16*)take(16515072ull*2);  // conv_t out -> conv_g out
  bf16* AE   = (bf16*)take(16515072ull*2);  // a_e
  bf16* TB   = (bf16*)take(16515072ull*2);  // branch-t attn out
  bf16* O1   = (bf16*)take(131072ull*2);
  bf16* OUTB = (bf16*)take(131072ull*2);
  bf16* SEB  = (bf16*)take(131072ull*2);
  bf16* SH   = (bf16*)take(126976ull*2);
  bf16* SCT  = (bf16*)take(126976ull*2);
  bf16* SO   = (bf16*)take(126976ull*2);
  bf16* SO2  = (bf16*)take(126976ull*2);
  bf16* SAE  = (bf16*)take(126976ull*2);
  bf16* XS   = (bf16*)take(126976ull*2);
  bf16* DO1  = (bf16*)take(2048ull*2);
  bf16* DOC  = (bf16*)take(2048ull*2);
  float* RK  = (float*)take(1024*4);
  float* PART= (float*)take(2016ull*2*4);
  float* STATS=(float*)take(32*4);
  float* DEC2= (float*)take(7168*4);
  float* C2  = (float*)take(26624*4);
  float* DEC3= (float*)take(26624*4);
  float* QC  = (float*)take(26624*4);
  float* KC  = (float*)take(26624*4);
  float* VC  = (float*)take(26624*4);
  float* DEC4= (float*)take(26624*4);
  float* C3  = (float*)take(26624*4);
  float* PET = (float*)take(16384*4);
  bf16* P_CE = (bf16*)take(49152ull*2);
  bf16* P_CT = (bf16*)take(49152ull*2);
  bf16* P_CG = (bf16*)take(49152ull*2);
  bf16* P_CES= (bf16*)take(49152ull*2);
  bf16* P_CTS= (bf16*)take(49152ull*2);
  bf16* P_WI = (bf16*)take(49152ull*2);
  bf16* P_WO = (bf16*)take(16384ull*2);
  (void)ws_size; (void)in_sizes; (void)n_in; (void)out_size;

  auto cdiv = [](long a, long b){ return (int)((a + b - 1)/b); };
  auto gemm = [&](const bf16* A, const bf16* Bpp, const float* bias, bf16* C, const bf16* mul,
                  int M, int N, int K, int a_lout, int a_lind, int lda, int NT, int n0t, int ldc, int act,
                  const float* lnst, int lngrp){
    dim3 g(cdiv(M,128), N/128, 1);
    if (lnst)
      k_gemm_mfma<false><<<g, 256, 0, stream>>>(A, Bpp, Bpp, bias, bias, C, C, mul,
                                                M, K, a_lout, a_lind, lda, NT, n0t, ldc, act, act, lnst, lngrp);
    else
      k_gemm_mfma<true><<<g, 256, 0, stream>>>(A, Bpp, Bpp, bias, bias, C, C, mul,
                                               M, K, a_lout, a_lind, lda, NT, n0t, ldc, act, act, nullptr, 0);
  };
  auto gemmz = [&](const bf16* A, const bf16* Bp1, const float* b1, bf16* C1, int act1,
                   const bf16* Bp2, const float* b2, bf16* C2p, int act2,
                   int M, int N, int K, int a_lout, int a_lind, int lda, int NT, int n0t, int ldc){
    dim3 g(cdiv(M,128), N/128, 2);
    k_gemm_mfma<true><<<g, 256, 0, stream>>>(A, Bp1, Bp2, b1, b2, C1, C2p, nullptr,
                                             M, K, a_lout, a_lind, lda, NT, n0t, ldc, act1, act2, nullptr, 0);
  };

  // ===== prep =====
  k_prep<<<1280, 256, 0, stream>>>(w_ce, w_ct, w_cg, w_ces, w_cts, wi, wo,
                                   P_CE, P_CT, P_CG, P_CES, P_CTS, P_WI, P_WO, PET);
  k_qprep<<<1, 256, 0, stream>>>(wi, bi, tgt1, tgt2, RK);
  k_embed8<<<8192, 256, 0, stream>>>(tokens, tab, PET, EMB);

  // ===== word level =====
  // batched conv pair: z0 CE->HB(elu), z1 CT->OB(tanh)
  gemmz(EMB, P_CE, b_ce, HB, 1, P_CT, b_ct, OB, 2, 129024, 128, 384, 126, 16384, 0, 8, 0, 128);

  // merged word attention: blocks [0,4096) HB->EMB (branch e); [4096,8192) OB->TB (branch t)
  k_attn_fused<126><<<8192, 256, 0, stream>>>(HB, OB, P_WI, bi, EMB, TB, 4096);
  // wo(elu): EMB -> AE
  gemm(EMB, P_WO, bo, AE, nullptr, 129024, 128, 128, 0, 0, 128, 8, 0, 128, 1, nullptr, 0);
  // wo(tanh)*AE: TB -> HB (product)
  gemm(TB, P_WO, bo, HB, AE, 129024, 128, 128, 0, 0, 128, 8, 0, 128, 2, nullptr, 0);

  // big LN stats over HB; apply fused into conv_g A-load
  k_ln_partial<<<2016, 256, 0, stream>>>(HB, PART, 1032192, 126);
  k_ln_fin<<<16, 256, 0, stream>>>(PART, STATS, 126, 1032192);

  // conv g (elu) with fused LN: HB -> OB [1024,124,128]
  gemm(HB, P_CG, b_cg, OB, nullptr, 126976, 128, 384, 124, 16128, 0, 8, 0, 128, 1, STATS, 1032192);

  // fused target-query attention
  k_attn_tgt<124><<<1024, 256, 0, stream>>>(OB, RK, wi, bi, O1);
  gemm(O1, P_WO, bo, OUTB, nullptr, 1024, 128, 128, 0, 0, 128, 8, 0, 128, 0, nullptr, 0);

  // ===== sentence level =====
  k_se<<<512, 256, 0, stream>>>(OUTB, PET, SEB);

  gemmz(SEB, P_CES, b_ces, SH, 1, P_CTS, b_cts, SCT, 2, 992, 128, 384, 62, 8192, 0, 8, 0, 128);

  // merged sentence attention: [0,64) SH->SO; [64,128) SCT->SO2
  k_attn_fused<62><<<128, 256, 0, stream>>>(SH, SCT, P_WI, bi, SO, SO2, 64);
  gemm(SO, P_WO, bo, SAE, nullptr, 992, 128, 128, 0, 0, 128, 8, 0, 128, 1, nullptr, 0);
  gemm(SO2, P_WO, bo, SH, SAE, 992, 128, 128, 0, 0, 128, 8, 0, 128, 2, nullptr, 0);

  k_ln_small_bf16<<<16, 256, 0, stream>>>(SH, XS, 7936);

  k_attn_tgt<62><<<16, 256, 0, stream>>>(XS, RK + 512, wi, bi, DO1);
  gemm(DO1, P_WO, bo, DOC, nullptr, 16, 128, 128, 0, 0, 128, 8, 0, 128, 0, nullptr, 0);

  // ===== decoder (hybrid) =====
  k_dec_a<<<16, 256, 0, stream>>>(DOC, w_mu, b_mu, w_lv, b_lv, epsb, w_di, b_di,
                                  dk_w, dk_b, dv_w, dv_b, wt1, bt1, dout, DEC2);
  k_convt<<<16*8, 256, 0, stream>>>(DEC2, wt2, bt2, C2, 16, 64, 128, 7, 13, 2, 1, 8);
  k_ln_small_f32<<<16, 256, 0, stream>>>(C2, DEC3, 1664, 1);
  k_chanproj3<<<cdiv(26624,256), 256, 0, stream>>>(DEC3, sq_w, sq_b, sk_w, sk_b, sv_w, sv_b,
                                                   QC, KC, VC, 16, 128, 13);
  k_dec_attn2<<<64, 256, 0, stream>>>(QC, KC, VC, DEC4);
  k_convt<<<16*8, 256, 0, stream>>>(DEC4, wt3, bt3, C3, 16, 128, 128, 13, 13, 1, 1, 8);
  k_ln_small_f32<<<16, 256, 0, stream>>>(C3, dout, 1664, 3);
}

// Round 19
// 605.755 us; speedup vs baseline: 1.0471x; 1.0195x over previous
//
#include <hip/hip_runtime.h>
#include <hip/hip_bf16.h>

typedef __hip_bfloat16 bf16;
typedef __attribute__((ext_vector_type(8))) short bf16x8;
typedef __attribute__((ext_vector_type(4))) float f32x4;

__device__ __forceinline__ float b2f(bf16 x){ return __bfloat162float(x); }
__device__ __forceinline__ bf16  f2b(float x){ return __float2bfloat16(x); }
__device__ __forceinline__ unsigned short b2u(bf16 x){ union{bf16 b; unsigned short u;} c; c.b = x; return c.u; }

#define LOG2E 1.4426950408889634f
#define QSC (0.17677669529663687f * LOG2E)

#define GLD16(gp, lp) __builtin_amdgcn_global_load_lds( \
    (const __attribute__((address_space(1))) void*)(gp), \
    (__attribute__((address_space(3))) void*)(lp), 16, 0, 0)

__device__ __forceinline__ float fexp2(float x){       // v_exp_f32 = 2^x, ~1 ulp
  float r; asm("v_exp_f32 %0, %1" : "=v"(r) : "v"(x)); return r;
}
__device__ __forceinline__ float fast_exp(float x){ return fexp2(x * LOG2E); }
__device__ __forceinline__ float eluf(float x){ return x > 0.f ? x : fast_exp(x) - 1.f; }
__device__ __forceinline__ float fast_tanh(float x){
  float cx = fminf(fmaxf(x, -15.f), 15.f);
  float t = fexp2(cx * (2.f*LOG2E));
  return (t - 1.f) / (t + 1.f);
}

#define PE_C (-0.07195578415606394f)  /* -ln(10000)/128 */

__device__ __forceinline__ float pe_val(int pos, int d){
  int j2 = d & ~1;
  float ang = (float)pos * expf((float)j2 * PE_C);
  return (d & 1) ? cosf(ang) : sinf(ang);
}

// ---------------- merged prep: 7 weight packs + PE table ----------------
__device__ __forceinline__ void pack_one(const float* __restrict__ W, bf16* __restrict__ out,
                                         int K, int N, int conv, int qscale, int t){
  int j = t & 7, lane = (t >> 3) & 63;
  int rest = t >> 9; int NT = N >> 4;
  int nt = rest % NT; int kb = rest / NT;
  int k = kb*32 + ((lane >> 4) << 3) + j;
  int n = nt*16 + (lane & 15);
  float v = conv ? W[n*384 + (k & 127)*3 + (k >> 7)] : W[(long)n*K + k];
  if (qscale && n < 128) v *= QSC;
  out[t] = f2b(v);
}

__global__ void k_prep(const float* __restrict__ w_ce, const float* __restrict__ w_ct,
                       const float* __restrict__ w_cg, const float* __restrict__ w_ces,
                       const float* __restrict__ w_cts, const float* __restrict__ wi,
                       const float* __restrict__ wo,
                       bf16* P_CE, bf16* P_CT, bf16* P_CG, bf16* P_CES, bf16* P_CTS,
                       bf16* P_WI, bf16* P_WO, float* __restrict__ pet){
  int bid = blockIdx.x;
  if (bid < 1152){
    int grp = bid / 192; int t = (bid % 192)*256 + threadIdx.x;
    const float* W; bf16* out; int K, N, conv, qs = 0;
    if      (grp == 0){ W = w_ce;  out = P_CE;  K=384; N=128; conv=1; }
    else if (grp == 1){ W = w_ct;  out = P_CT;  K=384; N=128; conv=1; }
    else if (grp == 2){ W = w_cg;  out = P_CG;  K=384; N=128; conv=1; }
    else if (grp == 3){ W = w_ces; out = P_CES; K=384; N=128; conv=1; }
    else if (grp == 4){ W = w_cts; out = P_CTS; K=384; N=128; conv=1; }
    else              { W = wi;    out = P_WI;  K=128; N=384; conv=0; qs=1; }
    pack_one(W, out, K, N, conv, qs, t);
  } else if (bid < 1216){
    int t = (bid - 1152)*256 + threadIdx.x;
    pack_one(wo, P_WO, 128, 128, 0, 0, t);
  } else {
    int i = (bid - 1216)*256 + threadIdx.x;
    if (i < 16384) pet[i] = pe_val(i >> 7, i & 127);
  }
}

// ---------------- q-prep ----------------
__global__ void k_qprep(const float* __restrict__ wi, const float* __restrict__ bi,
                        const float* __restrict__ t1, const float* __restrict__ t2,
                        float* __restrict__ rkv){
  int tid = threadIdx.x;
  __shared__ float qps[256];
  {
    int which = tid >> 7, jj = tid & 127;
    const float* t = which ? t2 : t1;
    float a = bi[jj];
    for (int i = 0; i < 128; ++i) a += wi[jj*128 + i] * t[i];
    qps[tid] = a;
  }
  __syncthreads();
  int i = tid & 127, which = tid >> 7;
  for (int h = 0; h < 4; ++h){
    float a = 0.f;
    for (int d = 0; d < 32; ++d) a += qps[which*128 + h*32 + d] * wi[(128 + h*32 + d)*128 + i];
    rkv[which*512 + h*128 + i] = a;
  }
}

// ---------------- embedding + positional encoding ----------------
__global__ void k_embed8(const int* __restrict__ tok, const float* __restrict__ tab,
                         const float* __restrict__ pet, bf16* __restrict__ out){
  int t = blockIdx.x*256 + threadIdx.x;        // < 2097152
  int q = t & 15;
  int flat = t >> 4; int w = flat & 127;
  int tk = tok[flat];
  const float* ta = tab + tk*128 + q*8;
  const float* pe = pet + (w << 7) + q*8;
  bf16 ob[8];
  #pragma unroll
  for (int i = 0; i < 8; ++i) ob[i] = f2b(ta[i] + pe[i]);
  *(f32x4*)(out + (size_t)t*8) = *(f32x4*)ob;
}

__global__ void k_se(const bf16* __restrict__ in, const float* __restrict__ pet, bf16* __restrict__ out){
  int idx = blockIdx.x*256 + threadIdx.x;      // < 131072
  int d = idx & 127; int n = (idx >> 7) & 63;
  out[idx] = f2b(b2f(in[idx]) + pet[(n << 7) + d]);
}

// ---------------- MFMA GEMM, double-buffered 1-barrier pipeline ----------------
// GLL=true: async global_load_lds staging (linear LDS dest, inverse-swizzled per-lane source).
// GLL=false: reg-staged path (supports fused LayerNorm on A load).
template<bool GLL>
__global__ __launch_bounds__(256)
void k_gemm_mfma(const bf16* __restrict__ A, const bf16* __restrict__ Bp_, const bf16* __restrict__ Bp2,
                 const float* __restrict__ bias_, const float* __restrict__ bias2,
                 bf16* __restrict__ C_, bf16* __restrict__ C2p,
                 const bf16* __restrict__ mul,
                 int M, int K, int a_lout, int a_lind, int lda,
                 int NT, int n0t, int ldc, int act_, int act2,
                 const float* __restrict__ lnst, int lngrp){
  const bf16* Bp = Bp_; const float* bias = bias_; bf16* C = C_; int act = act_;
  if (blockIdx.z){ Bp = Bp2; bias = bias2; C = C2p; act = act2; }

  __shared__ f32x4 AsV[2][512];                 // 2 x 8 KB
  char* As0 = (char*)AsV[0];
  char* As1 = (char*)AsV[1];
  int tid = threadIdx.x;
  int lane = tid & 63, wave = tid >> 6;
  int wm = wave >> 1, wn = wave & 1;
  int m0 = blockIdx.x*128;
  int by = blockIdx.y;

  long offA[2]; bool okA[2]; float lnm[2], lnr[2]; int sbyte[2];
  #pragma unroll
  for (int p = 0; p < 2; ++p){
    int e = tid + p*256;
    int row, kq;
    if (GLL){
      // inverse of slot swizzle: slot x holds (row,kq) with x = (row<<2|kq) ^ (row&7)
      int x = e;
      row = (((x >> 3) << 1) | (((x >> 2) ^ (x >> 4)) & 1)) & 127;
      kq  = ((((x >> 1) ^ (x >> 3)) & 1) << 1) | ((x ^ (x >> 2) ^ (x >> 4)) & 1);
    } else {
      row = e >> 2; kq = e & 3;
    }
    int m = m0 + row;
    okA[p] = (m < M);
    long off = 0;
    if (okA[p]){
      off = (a_lout > 0) ? (long)(m / a_lout)*a_lind + (long)(m % a_lout)*128 + kq*8
                         : (long)m*lda + kq*8;
    }
    offA[p] = off;
    lnm[p] = 0.f; lnr[p] = 1.f;
    if (!GLL && lnst && okA[p]){ int g = (int)(off / (long)lngrp); lnm[p] = lnst[2*g]; lnr[p] = lnst[2*g+1]; }
    sbyte[p] = (row*64 + kq*16) ^ ((row & 7) << 4);
  }

  const bf16* bptr[4];
  size_t bstep = (size_t)NT*512;
  #pragma unroll
  for (int fn = 0; fn < 4; ++fn){
    int ntile = n0t + by*8 + wn*4 + fn;
    bptr[fn] = Bp + ((size_t)ntile*64 + lane)*8;
  }
  int abyte[4];
  #pragma unroll
  for (int fm = 0; fm < 4; ++fm){
    int row = wm*64 + fm*16 + (lane & 15);
    abyte[fm] = (row*64 + ((lane >> 4) << 4)) ^ ((row & 7) << 4);
  }

  f32x4 acc[4][4];
  #pragma unroll
  for (int i = 0; i < 4; ++i)
    #pragma unroll
    for (int j = 0; j < 4; ++j) acc[i][j] = (f32x4){0.f,0.f,0.f,0.f};

  int nk = K >> 5;

  if constexpr (GLL){
    int ldsw = (tid >> 6)*1024;
    #pragma unroll
    for (int p = 0; p < 2; ++p)
      GLD16(A + offA[p], As0 + p*4096 + ldsw);
    __syncthreads();
    for (int kb = 0; kb < nk; ++kb){
      char* cur = (kb & 1) ? As1 : As0;
      char* nxt = (kb & 1) ? As0 : As1;
      bool more = (kb + 1) < nk;
      if (more){
        #pragma unroll
        for (int p = 0; p < 2; ++p)
          GLD16(A + offA[p] + (kb+1)*32, nxt + p*4096 + ldsw);
      }
      bf16x8 bfr[4];
      #pragma unroll
      for (int fn = 0; fn < 4; ++fn) bfr[fn] = *(const bf16x8*)(bptr[fn] + (size_t)kb*bstep);
      bf16x8 afr[4];
      #pragma unroll
      for (int fm = 0; fm < 4; ++fm) afr[fm] = *(const bf16x8*)(cur + abyte[fm]);
      #pragma unroll
      for (int fm = 0; fm < 4; ++fm)
        #pragma unroll
        for (int fn = 0; fn < 4; ++fn)
          acc[fm][fn] = __builtin_amdgcn_mfma_f32_16x16x32_bf16(afr[fm], bfr[fn], acc[fm][fn], 0, 0, 0);
      __syncthreads();
    }
  } else {
    auto loadA = [&](int p, int kb)->float4{
      float4 v = make_float4(0.f,0.f,0.f,0.f);
      if (okA[p]){
        v = *(const float4*)(A + offA[p] + kb*32);
        if (lnst){
          bf16* pp = (bf16*)&v; bf16 oo[8];
          #pragma unroll
          for (int u = 0; u < 8; ++u) oo[u] = f2b((b2f(pp[u]) - lnm[p]) * lnr[p]);
          v = *(float4*)&oo[0];
        }
      }
      return v;
    };
    float4 va0 = loadA(0, 0), va1 = loadA(1, 0);
    *(float4*)(As0 + sbyte[0]) = va0;
    *(float4*)(As0 + sbyte[1]) = va1;
    __syncthreads();
    for (int kb = 0; kb < nk; ++kb){
      char* cur = (kb & 1) ? As1 : As0;
      char* nxt = (kb & 1) ? As0 : As1;
      bool more = (kb + 1) < nk;
      if (more){ va0 = loadA(0, kb+1); va1 = loadA(1, kb+1); }  // issue early
      bf16x8 bfr[4];
      #pragma unroll
      for (int fn = 0; fn < 4; ++fn) bfr[fn] = *(const bf16x8*)(bptr[fn] + (size_t)kb*bstep);
      bf16x8 afr[4];
      #pragma unroll
      for (int fm = 0; fm < 4; ++fm) afr[fm] = *(const bf16x8*)(cur + abyte[fm]);
      #pragma unroll
      for (int fm = 0; fm < 4; ++fm)
        #pragma unroll
        for (int fn = 0; fn < 4; ++fn)
          acc[fm][fn] = __builtin_amdgcn_mfma_f32_16x16x32_bf16(afr[fm], bfr[fn], acc[fm][fn], 0, 0, 0);
      if (more){
        *(float4*)(nxt + sbyte[0]) = va0;   // write late
        *(float4*)(nxt + sbyte[1]) = va1;
      }
      __syncthreads();
    }
  }

  #pragma unroll
  for (int fm = 0; fm < 4; ++fm){
    #pragma unroll
    for (int r = 0; r < 4; ++r){
      int m = m0 + wm*64 + fm*16 + ((lane >> 4) << 2) + r;
      if (m >= M) continue;
      #pragma unroll
      for (int fn = 0; fn < 4; ++fn){
        int n = by*128 + wn*64 + fn*16 + (lane & 15);
        float v = acc[fm][fn][r] + (bias ? bias[n] : 0.f);
        if (act == 1) v = eluf(v);
        else if (act == 2) v = fast_tanh(v);
        if (mul) v *= b2f(mul[(long)m*ldc + n]);
        C[(long)m*ldc + n] = f2b(v);
      }
    }
  }
}

// ---------------- fused QKV-projection + MFMA self-attention ----------------
// Two independent branches merged into one dispatch: blocks >= nhalf use (X2, o2).
// One wave per 16-row tile (NW = MT waves/block): same 56 KB LDS but 2x resident
// waves per CU vs the 4-wave version (occupancy 25% -> 50% theoretical).
template<int L>
__global__ __launch_bounds__(((L + 31) / 32) * 128)
void k_attn_fused(const bf16* __restrict__ X, const bf16* __restrict__ X2,
                  const bf16* __restrict__ Pwi, const float* __restrict__ bi,
                  bf16* __restrict__ o, bf16* __restrict__ o2, int nhalf){
  constexpr int KB  = (L + 31) / 32;   // PV K-steps
  constexpr int MT  = KB * 2;          // 16-row tiles
  constexpr int NW  = MT;              // waves per block (one per tile)
  constexpr int NTH = NW * 64;         // threads per block
  constexpr int NP  = KB * 32;         // padded seq len
  constexpr int PRS = NP * 2;          // P row stride bytes

  __shared__ alignas(16) char As[NP*256];   // X tile; aliased by Pb
  __shared__ alignas(16) char Qb[NP*64];
  __shared__ alignas(16) char Kb[NP*64];
  __shared__ alignas(16) char Vt[32*PRS];
  char* Pb = As;

  int tid = threadIdx.x;
  int bid = blockIdx.x;
  const bf16* Xp = X; bf16* op = o;
  if (bid >= nhalf){ Xp = X2; op = o2; bid -= nhalf; }
  int s = bid >> 2, h = bid & 3;
  const bf16* xb = Xp + (size_t)s*L*128;

  {
    constexpr int NCH = (NP*16)/NTH;
    int ldsw = (tid >> 6)*1024;
    #pragma unroll
    for (int p = 0; p < NCH; ++p){
      int x = p*NTH + tid;
      int row = x >> 4;
      int c = (x & 15) ^ (row & 7);
      const bf16* gp = (row < L) ? (xb + (size_t)row*128 + c*8) : xb;
      GLD16(gp, As + p*(NTH*16) + ldsw);
    }
  }
  __syncthreads();

  int lane = tid & 63, wave = tid >> 6;
  int col = lane & 15;
  int mtile = wave;                    // each wave owns one 16-row tile

  // ---- projection ----
  __builtin_amdgcn_s_setprio(1);
  {
    int arow = mtile*16 + col;
    bf16x8 a4[4];
    #pragma unroll
    for (int kb = 0; kb < 4; ++kb)
      a4[kb] = *(const bf16x8*)(As + ((arow*256 + kb*64 + ((lane >> 4) << 4)) ^ ((arow & 7) << 4)));
    #pragma unroll
    for (int which = 0; which < 3; ++which){
      f32x4 av[2];
      #pragma unroll
      for (int nt = 0; nt < 2; ++nt){
        int ntile = which*8 + h*2 + nt;
        float bia = bi[which*128 + h*32 + nt*16 + col];
        if (which == 0) bia *= QSC;
        av[nt] = (f32x4){bia, bia, bia, bia};
        #pragma unroll
        for (int kb = 0; kb < 4; ++kb){
          bf16x8 bfr = *(const bf16x8*)(Pwi + (((size_t)kb*24 + ntile)*64 + lane)*8);
          av[nt] = __builtin_amdgcn_mfma_f32_16x16x32_bf16(a4[kb], bfr, av[nt], 0, 0, 0);
        }
      }
      #pragma unroll
      for (int r = 0; r < 4; ++r){
        int row = mtile*16 + ((lane >> 4) << 2) + r;
        if (which < 2){
          unsigned pk = (unsigned)b2u(f2b(av[0][r])) | ((unsigned)b2u(f2b(av[1][r])) << 16);
          char* dst = which ? Kb : Qb;
          *(unsigned*)(dst + ((row*64 + col*4) ^ ((row & 7) << 4))) = pk;
        } else {
          int pos = (row & 15)*MT + (row >> 4);
          #pragma unroll
          for (int nt = 0; nt < 2; ++nt){
            int d = nt*16 + col;
            *(bf16*)(Vt + ((d*PRS + pos*2) ^ ((d & 7) << 4))) = f2b(av[nt][r]);
          }
        }
      }
    }
  }
  __builtin_amdgcn_s_setprio(0);
  __syncthreads();

  // ---- QK^T (scores in log2 units) ----
  f32x4 acc[MT];
  #pragma unroll
  for (int nt = 0; nt < MT; ++nt) acc[nt] = (f32x4){0.f,0.f,0.f,0.f};

  bf16x8 af;
  {
    int row = mtile*16 + col;
    af = *(const bf16x8*)(Qb + ((row*64 + ((lane >> 4) << 4)) ^ ((row & 7) << 4)));
  }
  __builtin_amdgcn_s_setprio(1);
  #pragma unroll
  for (int nt = 0; nt < MT; ++nt){
    int rk2 = nt*16 + col;
    bf16x8 bfk = *(const bf16x8*)(Kb + ((rk2*64 + ((lane >> 4) << 4)) ^ ((rk2 & 7) << 4)));
    acc[nt] = __builtin_amdgcn_mfma_f32_16x16x32_bf16(af, bfk, acc[nt], 0, 0, 0);
  }
  __builtin_amdgcn_s_setprio(0);

  // ---- softmax: mask last col-tile, single v_exp, packed P write, deferred normalize ----
  const bool lastMask = col >= (L - (MT-1)*16);
  float pinv[4];
  #pragma unroll
  for (int r = 0; r < 4; ++r){
    float mx = -1e30f;
    #pragma unroll
    for (int nt = 0; nt < MT; ++nt){
      float v = acc[nt][r];
      if (nt == MT-1 && lastMask){ v = -1e30f; acc[nt][r] = v; }
      mx = fmaxf(mx, v);
    }
    mx = fmaxf(mx, __shfl_xor(mx, 1));
    mx = fmaxf(mx, __shfl_xor(mx, 2));
    mx = fmaxf(mx, __shfl_xor(mx, 4));
    mx = fmaxf(mx, __shfl_xor(mx, 8));
    float sum = 0.f;
    bf16 prow[MT];
    #pragma unroll
    for (int nt = 0; nt < MT; ++nt){
      float p = fexp2(acc[nt][r] - mx);
      prow[nt] = f2b(p);
      sum += p;
    }
    sum += __shfl_xor(sum, 1);
    sum += __shfl_xor(sum, 2);
    sum += __shfl_xor(sum, 4);
    sum += __shfl_xor(sum, 8);
    pinv[r] = 1.f / sum;
    int row = mtile*16 + ((lane >> 4) << 2) + r;
    char* dst = Pb + ((row*PRS + col*(MT*2)) ^ ((row & 7) << 4));
    if constexpr (MT == 8) *(f32x4*)dst = *(f32x4*)prow;
    else                   *(float2*)dst = *(float2*)prow;
  }

  // ---- PV (same-wave rows; no barrier), normalize at output ----
  {
    f32x4 o0 = (f32x4){0.f,0.f,0.f,0.f}, o1 = (f32x4){0.f,0.f,0.f,0.f};
    __builtin_amdgcn_s_setprio(1);
    #pragma unroll
    for (int kb = 0; kb < KB; ++kb){
      int row = mtile*16 + col;
      bf16x8 pa = *(const bf16x8*)(Pb + ((row*PRS + kb*64 + ((lane >> 4) << 4)) ^ ((row & 7) << 4)));
      int d0 = col;
      bf16x8 v0 = *(const bf16x8*)(Vt + ((d0*PRS + kb*64 + ((lane >> 4) << 4)) ^ ((d0 & 7) << 4)));
      bf16x8 v1 = *(const bf16x8*)(Vt + (((d0+16)*PRS + kb*64 + ((lane >> 4) << 4)) ^ (((d0+16) & 7) << 4)));
      o0 = __builtin_amdgcn_mfma_f32_16x16x32_bf16(pa, v0, o0, 0, 0, 0);
      o1 = __builtin_amdgcn_mfma_f32_16x16x32_bf16(pa, v1, o1, 0, 0, 0);
    }
    __builtin_amdgcn_s_setprio(0);
    #pragma unroll
    for (int r = 0; r < 4; ++r){
      int row = mtile*16 + ((lane >> 4) << 2) + r;
      if (row < L){
        size_t ob = ((size_t)s*L + row)*128 + h*32 + col;
        op[ob]      = f2b(o0[r] * pinv[r]);
        op[ob + 16] = f2b(o1[r] * pinv[r]);
      }
    }
  }
}

// ---------------- fused target-query attention ----------------
template<int L>
__global__ __launch_bounds__(256)
void k_attn_tgt(const bf16* __restrict__ hin, const float* __restrict__ rk,
                const float* __restrict__ wi, const float* __restrict__ bi,
                bf16* __restrict__ outp){
  __shared__ alignas(16) char Hs[L*256];
  __shared__ float RKs[512];
  __shared__ float Ps[512];
  __shared__ float Cs[512];
  int tid = threadIdx.x, lane = tid & 63, wave = tid >> 6;
  int s = blockIdx.x;
  const bf16* hb = hin + (size_t)s*L*128;
  for (int e = tid; e < L*16; e += 256){
    int row = e >> 4, c = e & 15;
    *(float4*)(Hs + row*256 + ((c ^ (row & 7)) << 4)) = *(const float4*)(hb + row*128 + c*8);
  }
  for (int e = tid; e < 512; e += 256) RKs[e] = rk[e];
  __syncthreads();

  int j0 = lane, j1 = lane + 64;
  float v0 = -1e30f, v1 = -1e30f;
  if (j0 < L){
    float a = 0.f;
    #pragma unroll
    for (int c = 0; c < 16; ++c){
      bf16x8 x = *(const bf16x8*)(Hs + j0*256 + ((c ^ (j0 & 7)) << 4));
      #pragma unroll
      for (int u = 0; u < 8; ++u) a += b2f(((bf16*)&x)[u]) * RKs[wave*128 + c*8 + u];
    }
    v0 = a * 0.17677669529663687f;
  }
  if (j1 < L){
    float a = 0.f;
    #pragma unroll
    for (int c = 0; c < 16; ++c){
      bf16x8 x = *(const bf16x8*)(Hs + j1*256 + ((c ^ (j1 & 7)) << 4));
      #pragma unroll
      for (int u = 0; u < 8; ++u) a += b2f(((bf16*)&x)[u]) * RKs[wave*128 + c*8 + u];
    }
    v1 = a * 0.17677669529663687f;
  }
  float mx = fmaxf(v0, v1);
  #pragma unroll
  for (int off = 32; off; off >>= 1) mx = fmaxf(mx, __shfl_xor(mx, off));
  float e0 = (j0 < L) ? fast_exp(v0 - mx) : 0.f;
  float e1 = (j1 < L) ? fast_exp(v1 - mx) : 0.f;
  float sum = e0 + e1;
  #pragma unroll
  for (int off = 32; off; off >>= 1) sum += __shfl_xor(sum, off);
  float inv = 1.f / sum;
  Ps[wave*128 + j0] = e0 * inv;
  Ps[wave*128 + j1] = e1 * inv;

  int i0 = lane*2;
  float c0 = 0.f, c1 = 0.f;
  for (int j = 0; j < L; ++j){
    float p = Ps[wave*128 + j];
    short2 w2 = *(const short2*)(Hs + j*256 + (((i0 >> 3) ^ (j & 7)) << 4) + (i0 & 7)*2);
    c0 += p * b2f(*(bf16*)&w2.x);
    c1 += p * b2f(*(bf16*)&w2.y);
  }
  Cs[wave*128 + i0]     = c0;
  Cs[wave*128 + i0 + 1] = c1;
  __syncthreads();

  if (tid < 128){
    int h2 = tid >> 5;
    float a = bi[256 + tid];
    const float* wr = wi + (size_t)(256 + tid)*128;
    for (int i = 0; i < 128; ++i) a += wr[i] * Cs[h2*128 + i];
    outp[(size_t)s*128 + tid] = f2b(a);
  }
}

// ---------------- big LayerNorm stats: partial / finalize ----------------
__global__ void k_ln_partial(const bf16* __restrict__ x, float* __restrict__ part, int GS, int P){
  int pi = blockIdx.x % P;
  int chunk8 = GS / P / 8;
  size_t base = (size_t)(blockIdx.x / P)*GS + (size_t)pi*(GS/P);
  float s = 0.f, s2 = 0.f;
  for (int i = threadIdx.x; i < chunk8; i += 256){
    f32x4 raw = *(const f32x4*)(x + base + (size_t)i*8);
    const bf16* xb = (const bf16*)&raw;
    #pragma unroll
    for (int j = 0; j < 8; ++j){ float v = b2f(xb[j]); s += v; s2 += v*v; }
  }
  #pragma unroll
  for (int off = 32; off; off >>= 1){ s += __shfl_xor(s, off); s2 += __shfl_xor(s2, off); }
  __shared__ float sh[8];
  int lane = threadIdx.x & 63, wv = threadIdx.x >> 6;
  if (lane == 0){ sh[wv] = s; sh[4 + wv] = s2; }
  __syncthreads();
  if (threadIdx.x == 0){
    part[blockIdx.x*2]     = sh[0]+sh[1]+sh[2]+sh[3];
    part[blockIdx.x*2 + 1] = sh[4]+sh[5]+sh[6]+sh[7];
  }
}

__global__ void k_ln_fin(const float* __restrict__ part, float* __restrict__ stats, int P, int GS){
  int g = blockIdx.x;
  float s = 0.f, s2 = 0.f;
  for (int i = threadIdx.x; i < P; i += 256){ s += part[(g*P + i)*2]; s2 += part[(g*P + i)*2 + 1]; }
  #pragma unroll
  for (int off = 32; off; off >>= 1){ s += __shfl_xor(s, off); s2 += __shfl_xor(s2, off); }
  __shared__ float sh[8];
  int lane = threadIdx.x & 63, wv = threadIdx.x >> 6;
  if (lane == 0){ sh[wv] = s; sh[4 + wv] = s2; }
  __syncthreads();
  if (threadIdx.x == 0){
    float S = sh[0]+sh[1]+sh[2]+sh[3], S2 = sh[4]+sh[5]+sh[6]+sh[7];
    float mean = S / GS;
    float var = S2 / GS - mean*mean;
    stats[g*2] = mean; stats[g*2 + 1] = rsqrtf(var + 1e-5f);
  }
}

// ---------------- small LN (bf16), one block per group ----------------
__global__ void k_ln_small_bf16(const bf16* __restrict__ x, bf16* __restrict__ y, int n){
  int g = blockIdx.x;
  const bf16* xb = x + (size_t)g*n;
  bf16* yb = y + (size_t)g*n;
  float s = 0.f, s2 = 0.f;
  for (int i = threadIdx.x; i < n; i += 256){ float v = b2f(xb[i]); s += v; s2 += v*v; }
  #pragma unroll
  for (int off = 32; off; off >>= 1){ s += __shfl_xor(s, off); s2 += __shfl_xor(s2, off); }
  __shared__ float sh[8];  __shared__ float ms[2];
  int lane = threadIdx.x & 63, wv = threadIdx.x >> 6;
  if (lane == 0){ sh[wv] = s; sh[4 + wv] = s2; }
  __syncthreads();
  if (threadIdx.x == 0){
    float S = sh[0]+sh[1]+sh[2]+sh[3], S2 = sh[4]+sh[5]+sh[6]+sh[7];
    float mean = S / n;
    ms[0] = mean; ms[1] = rsqrtf(S2 / n - mean*mean + 1e-5f);
  }
  __syncthreads();
  float mean = ms[0], inv = ms[1];
  for (int i = threadIdx.x; i < n; i += 256) yb[i] = f2b((b2f(xb[i]) - mean)*inv);
}

// ---------------- small LN (f32), one block per group ----------------
__global__ void k_ln_small_f32(const float* __restrict__ x, float* __restrict__ y, int n, int act){
  int g = blockIdx.x;
  const float* xb = x + (size_t)g*n;
  float* yb = y + (size_t)g*n;
  float s = 0.f, s2 = 0.f;
  for (int i = threadIdx.x; i < n; i += 256){ float v = xb[i]; s += v; s2 += v*v; }
  #pragma unroll
  for (int off = 32; off; off >>= 1){ s += __shfl_xor(s, off); s2 += __shfl_xor(s2, off); }
  __shared__ float sh[8];  __shared__ float ms[2];
  int lane = threadIdx.x & 63, wv = threadIdx.x >> 6;
  if (lane == 0){ sh[wv] = s; sh[4 + wv] = s2; }
  __syncthreads();
  if (threadIdx.x == 0){
    float S = sh[0]+sh[1]+sh[2]+sh[3], S2 = sh[4]+sh[5]+sh[6]+sh[7];
    float mean = S / n;
    ms[0] = mean; ms[1] = rsqrtf(S2 / n - mean*mean + 1e-5f);
  }
  __syncthreads();
  float mean = ms[0], inv = ms[1];
  for (int i = threadIdx.x; i < n; i += 256){
    float v = (xb[i] - mean)*inv;
    if (act == 1) v = eluf(v);
    else if (act == 3) v = 1.f/(1.f + fast_exp(-v));
    yb[i] = v;
  }
}

// ---------------- decoder stage A (tiny front chain), one block per b ----------------
__global__ __launch_bounds__(256)
void k_dec_a(const bf16* __restrict__ DOC,
             const float* __restrict__ w_mu, const float* __restrict__ b_mu,
             const float* __restrict__ w_lv, const float* __restrict__ b_lv,
             const float* __restrict__ eps,
             const float* __restrict__ w_di, const float* __restrict__ b_di,
             const float* __restrict__ dk_w, const float* __restrict__ dk_b,
             const float* __restrict__ dv_w, const float* __restrict__ dv_b,
             const float* __restrict__ wt1, const float* __restrict__ bt1,
             float* __restrict__ dout, float* __restrict__ DEC2){
  int b = blockIdx.x, tid = threadIdx.x;
  __shared__ float Zs[128], H3[128], KD[128], VD[128], D1[128];
  __shared__ float C1[448];
  __shared__ float sc[64];
  __shared__ float red[8], ms[2];

  if (tid < 128){
    const bf16* dr = DOC + b*128;
    float mu = b_mu[tid], lv = b_lv[tid];
    for (int i = 0; i < 128; ++i){
      float x = b2f(dr[i]);
      mu += x * w_mu[tid*128 + i];
      lv += x * w_lv[tid*128 + i];
    }
    dout[26624 + b*128 + tid] = mu;
    dout[28672 + b*128 + tid] = lv;
    Zs[tid] = mu + eps[b*128 + tid] * fast_exp(0.5f*lv);
  }
  __syncthreads();
  if (tid < 128){
    float a = b_di[tid];
    for (int i = 0; i < 128; ++i) a += Zs[i] * w_di[tid*128 + i];
    H3[tid] = a;
  }
  __syncthreads();
  if (tid < 128){
    int l = tid & 3, o2 = tid >> 2;
    float ak = dk_b[o2], av = dv_b[o2];
    for (int i = 0; i < 32; ++i){
      float xv = H3[i*4 + l];
      ak += dk_w[o2*32 + i]*xv;
      av += dv_w[o2*32 + i]*xv;
    }
    KD[tid] = ak; VD[tid] = av;
  }
  __syncthreads();
  if (tid < 64){
    int h = tid >> 4, l = (tid >> 2) & 3, m = tid & 3;
    float a = 0.f;
    #pragma unroll
    for (int d = 0; d < 8; ++d) a += KD[(h*8+d)*4 + l] * VD[(h*8+d)*4 + m];
    sc[tid] = a * 0.35355339059327373f;
  }
  __syncthreads();
  if (tid < 16){
    int base = tid*4;
    float mx = fmaxf(fmaxf(sc[base],sc[base+1]),fmaxf(sc[base+2],sc[base+3]));
    float e0=fast_exp(sc[base]-mx), e1=fast_exp(sc[base+1]-mx), e2=fast_exp(sc[base+2]-mx), e3=fast_exp(sc[base+3]-mx);
    float inv = 1.f/(e0+e1+e2+e3);
    sc[base]=e0*inv; sc[base+1]=e1*inv; sc[base+2]=e2*inv; sc[base+3]=e3*inv;
  }
  __syncthreads();
  if (tid < 128){
    int h = tid >> 5, rem = tid & 31, l = rem >> 3, d = rem & 7;
    float a = 0.f;
    #pragma unroll
    for (int m = 0; m < 4; ++m) a += sc[h*16 + l*4 + m] * VD[(h*8+d)*4 + m];
    D1[tid] = eluf(a);
  }
  __syncthreads();
  for (int idx = tid; idx < 448; idx += 256){
    int co = idx / 7, lo = idx % 7;
    float a = bt1[co];
    for (int k = 0; k < 3; ++k){
      int t = lo + 1 - k;
      if (t < 0 || (t & 1)) continue;
      int li = t >> 1; if (li >= 4) continue;
      float aa = 0.f;
      for (int ci = 0; ci < 32; ++ci) aa += D1[ci*4 + li] * wt1[ci*192 + co*3 + k];
      a += aa;
    }
    C1[idx] = a;
  }
  __syncthreads();
  {
    float s = 0.f, s2 = 0.f;
    for (int i = tid; i < 448; i += 256){ float v = C1[i]; s += v; s2 += v*v; }
    #pragma unroll
    for (int o = 32; o; o >>= 1){ s += __shfl_xor(s, o); s2 += __shfl_xor(s2, o); }
    int lane = tid & 63, wv = tid >> 6;
    if (lane == 0){ red[wv] = s; red[4+wv] = s2; }
    __syncthreads();
    if (tid == 0){
      float S = red[0]+red[1]+red[2]+red[3], S2 = red[4]+red[5]+red[6]+red[7];
      float mean = S/448.f; ms[0] = mean; ms[1] = rsqrtf(S2/448.f - mean*mean + 1e-5f);
    }
    __syncthreads();
    float mean = ms[0], inv = ms[1];
    for (int i = tid; i < 448; i += 256)
      DEC2[b*448 + i] = eluf((C1[i]-mean)*inv);
  }
}

// three channel-projections sharing one input read
__global__ void k_chanproj3(const float* __restrict__ x,
                            const float* __restrict__ w1, const float* __restrict__ b1,
                            const float* __restrict__ w2, const float* __restrict__ b2,
                            const float* __restrict__ w3, const float* __restrict__ b3,
                            float* __restrict__ y1, float* __restrict__ y2, float* __restrict__ y3,
                            int Bn, int C, int L){
  int idx = blockIdx.x*256 + threadIdx.x;
  if (idx >= Bn*C*L) return;
  int l = idx % L; int t2 = idx / L; int o = t2 % C; int b = t2 / C;
  float a1 = b1[o], a2 = b2[o], a3 = b3[o];
  const float* xb = x + (size_t)b*C*L + l;
  for (int i = 0; i < C; ++i){
    float xv = xb[i*L];
    a1 += w1[(size_t)o*C + i]*xv;
    a2 += w2[(size_t)o*C + i]*xv;
    a3 += w3[(size_t)o*C + i]*xv;
  }
  y1[idx] = a1; y2[idx] = a2; y3[idx] = a3;
}

__global__ __launch_bounds__(256)
void k_dec_attn2(const float* __restrict__ qc, const float* __restrict__ kc,
                 const float* __restrict__ vc, float* __restrict__ out){
  int b = blockIdx.x >> 2, h = blockIdx.x & 3, tid = threadIdx.x;
  __shared__ float sc[169];
  const float* qb = qc + b*1664 + h*416;
  const float* kb = kc + b*1664 + h*416;
  const float* vb = vc + b*1664 + h*416;
  if (tid < 169){
    int l = tid/13, m = tid - l*13;
    float a = 0.f;
    #pragma unroll
    for (int d = 0; d < 32; ++d) a += qb[d*13 + l] * kb[d*13 + m];
    sc[tid] = a * 0.17677669529663687f;
  }
  __syncthreads();
  if (tid < 13){
    float mx = -1e30f;
    for (int m = 0; m < 13; ++m) mx = fmaxf(mx, sc[tid*13 + m]);
    float s = 0.f;
    for (int m = 0; m < 13; ++m){ float p = fast_exp(sc[tid*13 + m] - mx); sc[tid*13 + m] = p; s += p; }
    float inv = 1.f/s;
    for (int m = 0; m < 13; ++m) sc[tid*13 + m] *= inv;
  }
  __syncthreads();
  for (int idx = tid; idx < 416; idx += 256){
    int l = idx >> 5, d = idx & 31;
    float a = 0.f;
    for (int m = 0; m < 13; ++m) a += sc[l*13 + m] * vb[m*32 + d];
    out[b*1664 + h*416 + idx] = eluf(a);
  }
}

// ConvTranspose1d (K=3), x staged in LDS
__global__ __launch_bounds__(256)
void k_convt(const float* __restrict__ x, const float* __restrict__ w,
             const float* __restrict__ bias, float* __restrict__ y,
             int Bn, int Ci, int Co, int Lin, int Lout, int stride, int pad, int nch){
  __shared__ float xs[1664];
  int b = blockIdx.x / nch;
  int c0 = (blockIdx.x % nch)*16;
  int tid = threadIdx.x;
  for (int i = tid; i < Ci*Lin; i += 256) xs[i] = x[(size_t)b*Ci*Lin + i];
  __syncthreads();
  int co = c0 + (tid & 15);
  int lo = tid >> 4;
  if (co >= Co || lo >= Lout) return;
  float a = bias[co];
  for (int k = 0; k < 3; ++k){
    int t = lo + pad - k;
    if (t < 0 || (t % stride)) continue;
    int li = t / stride;
    if (li >= Lin) continue;
    float aa = 0.f;
    for (int ci = 0; ci < Ci; ++ci) aa += xs[ci*Lin + li] * w[(size_t)ci*Co*3 + co*3 + k];
    a += aa;
  }
  y[(size_t)b*Co*Lout + co*Lout + lo] = a;
}

// =====================================================================
extern "C" void kernel_launch(void* const* d_in, const int* in_sizes, int n_in,
                              void* d_out, int out_size, void* d_ws, size_t ws_size,
                              hipStream_t stream){
  const int*   tokens = (const int*)  d_in[0];
  const float* tab    = (const float*)d_in[1];
  const float* w_ce = (const float*)d_in[2];  const float* b_ce = (const float*)d_in[3];
  const float* w_ct = (const float*)d_in[4];  const float* b_ct = (const float*)d_in[5];
  const float* w_cg = (const float*)d_in[6];  const float* b_cg = (const float*)d_in[7];
  const float* w_ces= (const float*)d_in[8];  const float* b_ces= (const float*)d_in[9];
  const float* w_cts= (const float*)d_in[10]; const float* b_cts= (const float*)d_in[11];
  const float* wi   = (const float*)d_in[12]; const float* bi   = (const float*)d_in[13];
  const float* wo   = (const float*)d_in[14]; const float* bo   = (const float*)d_in[15];
  const float* tgt1 = (const float*)d_in[16]; const float* tgt2 = (const float*)d_in[17];
  const float* w_mu = (const float*)d_in[18]; const float* b_mu = (const float*)d_in[19];
  const float* w_lv = (const float*)d_in[20]; const float* b_lv = (const float*)d_in[21];
  const float* w_di = (const float*)d_in[22]; const float* b_di = (const float*)d_in[23];
  const float* epsb = (const float*)d_in[24];
  const float* dk_w = (const float*)d_in[25]; const float* dk_b = (const float*)d_in[26];
  const float* dv_w = (const float*)d_in[27]; const float* dv_b = (const float*)d_in[28];
  const float* wt1  = (const float*)d_in[29]; const float* bt1  = (const float*)d_in[30];
  const float* wt2  = (const float*)d_in[31]; const float* bt2  = (const float*)d_in[32];
  const float* sq_w = (const float*)d_in[33]; const float* sq_b = (const float*)d_in[34];
  const float* sk_w = (const float*)d_in[35]; const float* sk_b = (const float*)d_in[36];
  const float* sv_w = (const float*)d_in[37]; const float* sv_b = (const float*)d_in[38];
  const float* wt3  = (const float*)d_in[39]; const float* bt3  = (const float*)d_in[40];

  float* dout = (float*)d_out;

  // ---- workspace carve ----
  char* ws = (char*)d_ws;
  size_t off = 0;
  auto take = [&](size_t bytes)->char*{ char* p = ws + off; off += (bytes + 255) & ~(size_t)255; return p; };
  bf16* EMB  = (bf16*)take(16777216ull*2);  // embeddings -> branch-e attn out
  bf16* HB   = (bf16*)take(16515072ull*2);  // conv_e out -> product P
  bf16* OB   = (bf16*)take(16515072ull*2);  // conv_t out -> conv_g out
  bf16* AE   = (bf16*)take(16515072ull*2);  // a_e
  bf16* TB   = (bf16*)take(16515072ull*2);  // branch-t attn out
  bf16* O1   = (bf16*)take(131072ull*2);
  bf16* OUTB = (bf16*)take(131072ull*2);
  bf16* SEB  = (bf16*)take(131072ull*2);
  bf16* SH   = (bf16*)take(126976ull*2);
  bf16* SCT  = (bf16*)take(126976ull*2);
  bf16* SO   = (bf16*)take(126976ull*2);
  bf16* SO2  = (bf16*)take(126976ull*2);
  bf16* SAE  = (bf16*)take(126976ull*2);
  bf16* XS   = (bf16*)take(126976ull*2);
  bf16* DO1  = (bf16*)take(2048ull*2);
  bf16* DOC  = (bf16*)take(2048ull*2);
  float* RK  = (float*)take(1024*4);
  float* PART= (float*)take(2016ull*2*4);
  float* STATS=(float*)take(32*4);
  float* DEC2= (float*)take(7168*4);
  float* C2  = (float*)take(26624*4);
  float* DEC3= (float*)take(26624*4);
  float* QC  = (float*)take(26624*4);
  float* KC  = (float*)take(26624*4);
  float* VC  = (float*)take(26624*4);
  float* DEC4= (float*)take(26624*4);
  float* C3  = (float*)take(26624*4);
  float* PET = (float*)take(16384*4);
  bf16* P_CE = (bf16*)take(49152ull*2);
  bf16* P_CT = (bf16*)take(49152ull*2);
  bf16* P_CG = (bf16*)take(49152ull*2);
  bf16* P_CES= (bf16*)take(49152ull*2);
  bf16* P_CTS= (bf16*)take(49152ull*2);
  bf16* P_WI = (bf16*)take(49152ull*2);
  bf16* P_WO = (bf16*)take(16384ull*2);
  (void)ws_size; (void)in_sizes; (void)n_in; (void)out_size;

  auto cdiv = [](long a, long b){ return (int)((a + b - 1)/b); };
  auto gemm = [&](const bf16* A, const bf16* Bpp, const float* bias, bf16* C, const bf16* mul,
                  int M, int N, int K, int a_lout, int a_lind, int lda, int NT, int n0t, int ldc, int act,
                  const float* lnst, int lngrp){
    dim3 g(cdiv(M,128), N/128, 1);
    if (lnst)
      k_gemm_mfma<false><<<g, 256, 0, stream>>>(A, Bpp, Bpp, bias, bias, C, C, mul,
                                                M, K, a_lout, a_lind, lda, NT, n0t, ldc, act, act, lnst, lngrp);
    else
      k_gemm_mfma<true><<<g, 256, 0, stream>>>(A, Bpp, Bpp, bias, bias, C, C, mul,
                                               M, K, a_lout, a_lind, lda, NT, n0t, ldc, act, act, nullptr, 0);
  };
  auto gemmz = [&](const bf16* A, const bf16* Bp1, const float* b1, bf16* C1, int act1,
                   const bf16* Bp2, const float* b2, bf16* C2p, int act2,
                   int M, int N, int K, int a_lout, int a_lind, int lda, int NT, int n0t, int ldc){
    dim3 g(cdiv(M,128), N/128, 2);
    k_gemm_mfma<true><<<g, 256, 0, stream>>>(A, Bp1, Bp2, b1, b2, C1, C2p, nullptr,
                                             M, K, a_lout, a_lind, lda, NT, n0t, ldc, act1, act2, nullptr, 0);
  };

  // ===== prep =====
  k_prep<<<1280, 256, 0, stream>>>(w_ce, w_ct, w_cg, w_ces, w_cts, wi, wo,
                                   P_CE, P_CT, P_CG, P_CES, P_CTS, P_WI, P_WO, PET);
  k_qprep<<<1, 256, 0, stream>>>(wi, bi, tgt1, tgt2, RK);
  k_embed8<<<8192, 256, 0, stream>>>(tokens, tab, PET, EMB);

  // ===== word level =====
  // batched conv pair: z0 CE->HB(elu), z1 CT->OB(tanh)
  gemmz(EMB, P_CE, b_ce, HB, 1, P_CT, b_ct, OB, 2, 129024, 128, 384, 126, 16384, 0, 8, 0, 128);

  // merged word attention (8 waves/block): [0,4096) HB->EMB; [4096,8192) OB->TB
  k_attn_fused<126><<<8192, 512, 0, stream>>>(HB, OB, P_WI, bi, EMB, TB, 4096);
  // wo(elu): EMB -> AE
  gemm(EMB, P_WO, bo, AE, nullptr, 129024, 128, 128, 0, 0, 128, 8, 0, 128, 1, nullptr, 0);
  // wo(tanh)*AE: TB -> HB (product)
  gemm(TB, P_WO, bo, HB, AE, 129024, 128, 128, 0, 0, 128, 8, 0, 128, 2, nullptr, 0);

  // big LN stats over HB; apply fused into conv_g A-load
  k_ln_partial<<<2016, 256, 0, stream>>>(HB, PART, 1032192, 126);
  k_ln_fin<<<16, 256, 0, stream>>>(PART, STATS, 126, 1032192);

  // conv g (elu) with fused LN: HB -> OB [1024,124,128]
  gemm(HB, P_CG, b_cg, OB, nullptr, 126976, 128, 384, 124, 16128, 0, 8, 0, 128, 1, STATS, 1032192);

  // fused target-query attention
  k_attn_tgt<124><<<1024, 256, 0, stream>>>(OB, RK, wi, bi, O1);
  gemm(O1, P_WO, bo, OUTB, nullptr, 1024, 128, 128, 0, 0, 128, 8, 0, 128, 0, nullptr, 0);

  // ===== sentence level =====
  k_se<<<512, 256, 0, stream>>>(OUTB, PET, SEB);

  gemmz(SEB, P_CES, b_ces, SH, 1, P_CTS, b_cts, SCT, 2, 992, 128, 384, 62, 8192, 0, 8, 0, 128);

  // merged sentence attention (4 waves/block): [0,64) SH->SO; [64,128) SCT->SO2
  k_attn_fused<62><<<128, 256, 0, stream>>>(SH, SCT, P_WI, bi, SO, SO2, 64);
  gemm(SO, P_WO, bo, SAE, nullptr, 992, 128, 128, 0, 0, 128, 8, 0, 128, 1, nullptr, 0);
  gemm(SO2, P_WO, bo, SH, SAE, 992, 128, 128, 0, 0, 128, 8, 0, 128, 2, nullptr, 0);

  k_ln_small_bf16<<<16, 256, 0, stream>>>(SH, XS, 7936);

  k_attn_tgt<62><<<16, 256, 0, stream>>>(XS, RK + 512, wi, bi, DO1);
  gemm(DO1, P_WO, bo, DOC, nullptr, 16, 128, 128, 0, 0, 128, 8, 0, 128, 0, nullptr, 0);

  // ===== decoder (hybrid) =====
  k_dec_a<<<16, 256, 0, stream>>>(DOC, w_mu, b_mu, w_lv, b_lv, epsb, w_di, b_di,
                                  dk_w, dk_b, dv_w, dv_b, wt1, bt1, dout, DEC2);
  k_convt<<<16*8, 256, 0, stream>>>(DEC2, wt2, bt2, C2, 16, 64, 128, 7, 13, 2, 1, 8);
  k_ln_small_f32<<<16, 256, 0, stream>>>(C2, DEC3, 1664, 1);
  k_chanproj3<<<cdiv(26624,256), 256, 0, stream>>>(DEC3, sq_w, sq_b, sk_w, sk_b, sv_w, sv_b,
                                                   QC, KC, VC, 16, 128, 13);
  k_dec_attn2<<<64, 256, 0, stream>>>(QC, KC, VC, DEC4);
  k_convt<<<16*8, 256, 0, stream>>>(DEC4, wt3, bt3, C3, 16, 128, 128, 13, 13, 1, 1, 8);
  k_ln_small_f32<<<16, 256, 0, stream>>>(C3, dout, 1664, 3);
}